// Round 16
// baseline (80.137 us; speedup 1.0000x reference)
//
#include <hip/hip_runtime.h>
#include <cstdint>

#define TAU_ 9.797958971132712f

typedef __attribute__((ext_vector_type(4))) float f32x4;
typedef __attribute__((ext_vector_type(8))) short short8;

#define DEV static __device__ __forceinline__

DEV unsigned short f2bf(float f){
  union { float f; unsigned u; } v; v.f = f;
  unsigned r = v.u + 0x7FFFu + ((v.u >> 16) & 1u);
  return (unsigned short)(r >> 16);
}
DEV float bf2f(unsigned short u){
  union { unsigned u; float f; } v; v.u = ((unsigned)u) << 16; return v.f;
}
DEV unsigned pack2bf(float a, float b){
  unsigned r;
  asm("v_cvt_pk_bf16_f32 %0, %1, %2" : "=v"(r) : "v"(a), "v"(b));
  return r;
}
DEV f32x4 ld_bf4(const unsigned short* p){
  uint2 r = *(const uint2*)p;
  f32x4 o;
  o[0] = bf2f((unsigned short)(r.x & 0xffff));
  o[1] = bf2f((unsigned short)(r.x >> 16));
  o[2] = bf2f((unsigned short)(r.y & 0xffff));
  o[3] = bf2f((unsigned short)(r.y >> 16));
  return o;
}
DEV float siluf_(float x){ return x / (1.f + __expf(-x)); }
DEV float logsigf_(float x){ return fminf(x, 0.f) - log1pf(__expf(-fabsf(x))); }

// ---------------- K1a: LayerNorm (blocks 0-511) + weight f32->bf16 convert (tail) ----------------
__global__ __launch_bounds__(256) void k1a_ln(
    const float* __restrict__ x, const float* __restrict__ ln_g, const float* __restrict__ ln_b,
    const float* __restrict__ w1, const float* __restrict__ w2, const float* __restrict__ wo,
    short* __restrict__ xnbf, short* __restrict__ w12bf, short* __restrict__ wobf)
{
  const int tid = threadIdx.x;
  if(blockIdx.x >= 512){
    const int idx4 = (blockIdx.x - 512) * 256 + tid;   // 216*256 = 55296 f32x4 units
    const float* src; short* dst; int off;
    if(idx4 < 18432)      { src = w1; dst = w12bf;         off = idx4; }
    else if(idx4 < 36864) { src = w2; dst = w12bf + 73728; off = idx4 - 18432; }
    else                  { src = wo; dst = wobf;          off = idx4 - 36864; }
    f32x4 v = *(const f32x4*)(src + off * 4);
    uint2 pk; pk.x = pack2bf(v[0], v[1]); pk.y = pack2bf(v[2], v[3]);
    *(uint2*)(dst + off * 4) = pk;
    return;
  }
  const int t = blockIdx.x * 16 + (tid >> 4);
  const int g = tid & 15;
  const float* xr = x + (long)t * 192 + g * 12;
  f32x4 v0 = *(const f32x4*)(xr);
  f32x4 v1 = *(const f32x4*)(xr + 4);
  f32x4 v2 = *(const f32x4*)(xr + 8);
  float s  = v0[0]+v0[1]+v0[2]+v0[3] + v1[0]+v1[1]+v1[2]+v1[3] + v2[0]+v2[1]+v2[2]+v2[3];
  float sq = v0[0]*v0[0]+v0[1]*v0[1]+v0[2]*v0[2]+v0[3]*v0[3]
           + v1[0]*v1[0]+v1[1]*v1[1]+v1[2]*v1[2]+v1[3]*v1[3]
           + v2[0]*v2[0]+v2[1]*v2[1]+v2[2]*v2[2]+v2[3]*v2[3];
  s  += __shfl_xor(s, 1);  s  += __shfl_xor(s, 2);  s  += __shfl_xor(s, 4);  s  += __shfl_xor(s, 8);
  sq += __shfl_xor(sq, 1); sq += __shfl_xor(sq, 2); sq += __shfl_xor(sq, 4); sq += __shfl_xor(sq, 8);
  const float mean = s * (1.f/192.f);
  const float rstd = rsqrtf(sq * (1.f/192.f) - mean * mean + 1e-5f);
  const int c0 = g * 12;
  f32x4 g0 = *(const f32x4*)(ln_g + c0),     b0 = *(const f32x4*)(ln_b + c0);
  f32x4 g1 = *(const f32x4*)(ln_g + c0 + 4), b1 = *(const f32x4*)(ln_b + c0 + 4);
  f32x4 g2 = *(const f32x4*)(ln_g + c0 + 8), b2 = *(const f32x4*)(ln_b + c0 + 8);
  unsigned pk[6];
  pk[0] = pack2bf((v0[0]-mean)*rstd*g0[0]+b0[0], (v0[1]-mean)*rstd*g0[1]+b0[1]);
  pk[1] = pack2bf((v0[2]-mean)*rstd*g0[2]+b0[2], (v0[3]-mean)*rstd*g0[3]+b0[3]);
  pk[2] = pack2bf((v1[0]-mean)*rstd*g1[0]+b1[0], (v1[1]-mean)*rstd*g1[1]+b1[1]);
  pk[3] = pack2bf((v1[2]-mean)*rstd*g1[2]+b1[2], (v1[3]-mean)*rstd*g1[3]+b1[3]);
  pk[4] = pack2bf((v2[0]-mean)*rstd*g2[0]+b2[0], (v2[1]-mean)*rstd*g2[1]+b2[1]);
  pk[5] = pack2bf((v2[2]-mean)*rstd*g2[2]+b2[2], (v2[3]-mean)*rstd*g2[3]+b2[3]);
  uint2* xo = (uint2*)(xnbf + (long)t * 192 + g * 12);
  xo[0] = make_uint2(pk[0], pk[1]);
  xo[1] = make_uint2(pk[2], pk[3]);
  xo[2] = make_uint2(pk[4], pk[5]);
}

// ---------------- K1b: dual GEMM, M-tile 128, bf16 weights ----------------
__global__ __launch_bounds__(256) void k1b_gemm(
    const short* __restrict__ xnbf, const short* __restrict__ w12bf,
    const float* __restrict__ b1, const float* __restrict__ b2,
    unsigned short* __restrict__ abf, unsigned short* __restrict__ bgate)
{
  __shared__ short wt[18432];                          // 96*192 bf16 = 36.9 KB
  const int tid = threadIdx.x;
  const int ntg = blockIdx.x & 7;
  const int t0 = (blockIdx.x >> 3) * 128;
  {
    const short* src = w12bf + (long)ntg * 96 * 192;
    #pragma unroll
    for(int i = 0; i < 9; i++){
      const int u = i * 256 + tid;                     // 16B unit, 0..2303
      const int row = u / 24;
      const int dst = (u * 16) ^ ((row & 7) << 4);
      *(short8*)((char*)wt + dst) = *(const short8*)(src + u * 8);
    }
  }
  __syncthreads();
  const int widx = tid >> 6, lane = tid & 63, qg = lane >> 4, l16 = lane & 15;
  const int m0 = t0 + widx * 32;
  f32x4 acc[2][6];
  #pragma unroll
  for(int mt = 0; mt < 2; mt++)
    #pragma unroll
    for(int nt = 0; nt < 6; nt++) acc[mt][nt] = (f32x4){0.f,0.f,0.f,0.f};
  const short* xrow0 = xnbf + (long)(m0 + l16) * 192;
  const short* xrow1 = xnbf + (long)(m0 + 16 + l16) * 192;
  #pragma unroll
  for(int kc = 0; kc < 6; kc++){
    short8 af0 = *(const short8*)(xrow0 + kc * 32 + 8 * qg);
    short8 af1 = *(const short8*)(xrow1 + kc * 32 + 8 * qg);
    #pragma unroll
    for(int nt = 0; nt < 6; nt++){
      const int row = nt * 16 + l16;
      int byte = row * 384 + (kc * 32 + 8 * qg) * 2;
      byte ^= (row & 7) << 4;
      short8 bfr = *(const short8*)((const char*)wt + byte);
      acc[0][nt] = __builtin_amdgcn_mfma_f32_16x16x32_bf16(af0, bfr, acc[0][nt], 0, 0, 0);
      acc[1][nt] = __builtin_amdgcn_mfma_f32_16x16x32_bf16(af1, bfr, acc[1][nt], 0, 0, 0);
    }
  }
  const int half = ntg >> 2;
  const float* bias = half ? b2 : b1;
  const int ncol = (ntg & 3) * 96;
  #pragma unroll
  for(int mt = 0; mt < 2; mt++){
    #pragma unroll
    for(int nt = 0; nt < 6; nt++){
      const int n = ncol + nt * 16 + l16;
      const float bs = bias[n];
      #pragma unroll
      for(int r = 0; r < 4; r++){
        const int trow = m0 + mt * 16 + 4 * qg + r;
        float v = acc[mt][nt][r] + bs;
        if(half) bgate[(long)trow * 384 + n] = f2bf(siluf_(v));
        else     abf[(long)trow * 384 + n] = f2bf(v);
      }
    }
  }
}

// ---------------- K2bv: dwconv+silu -> qkbuf bf16, q/k proj -> bf16, v -> vbf + vtbf^T ----
__global__ __launch_bounds__(256) void k2bv(
    const unsigned short* __restrict__ abf,
    const float* __restrict__ cw, const float* __restrict__ cb,
    const float* __restrict__ qw, const float* __restrict__ qb,
    const float* __restrict__ kw, const float* __restrict__ kb,
    const float* __restrict__ vw, const float* __restrict__ vb,
    unsigned short* __restrict__ qkbf, short* __restrict__ qbf, short* __restrict__ kbf,
    short* __restrict__ vbf, short* __restrict__ vtbf)
{
  __shared__ float vt[64][97];
  const int tid = threadIdx.x;
  const int bh = blockIdx.x >> 4;
  const int b = bh >> 2, h = bh & 3;
  const int s0 = (blockIdx.x & 15) << 6;
  #pragma unroll
  for(int it = 0; it < 6; it++){
    const int f = it * 256 + tid;                     // 64 sl * 24 c4l
    const int sl = f / 24, c4l = f % 24;
    const int c4 = h * 24 + c4l;
    const int s = s0 + sl;
    const long t = (long)b * 1024 + s;
    const long abase = t * 384 + c4 * 4;
    f32x4 am = ld_bf4(abf + abase);
    f32x4 al = (s > 0)    ? ld_bf4(abf + abase - 384) : (f32x4){0.f,0.f,0.f,0.f};
    f32x4 ar = (s < 1023) ? ld_bf4(abf + abase + 384) : (f32x4){0.f,0.f,0.f,0.f};
    f32x4 cw0 = *(const f32x4*)(cw + c4 * 12);
    f32x4 cw1 = *(const f32x4*)(cw + c4 * 12 + 4);
    f32x4 cw2 = *(const f32x4*)(cw + c4 * 12 + 8);
    f32x4 cb4 = *(const f32x4*)(cb + c4 * 4);
    f32x4 in;
    in[0] = siluf_(cb4[0] + al[0]*cw0[0] + am[0]*cw0[1] + ar[0]*cw0[2]);
    in[1] = siluf_(cb4[1] + al[1]*cw0[3] + am[1]*cw1[0] + ar[1]*cw1[1]);
    in[2] = siluf_(cb4[2] + al[2]*cw1[2] + am[2]*cw1[3] + ar[2]*cw2[0]);
    in[3] = siluf_(cb4[3] + al[3]*cw2[1] + am[3]*cw2[2] + ar[3]*cw2[3]);
    {
      uint2 pk; pk.x = pack2bf(in[0], in[1]); pk.y = pack2bf(in[2], in[3]);
      *(uint2*)(qkbf + abase) = pk;
    }
    const long base = ((long)(b * 4 + h) * 1024 + s) * 96 + c4l * 4;
    {
      const float* w = qw + c4 * 16;
      float v0 = qb[c4*4+0] + w[0]*in[0]  + w[1]*in[1]  + w[2]*in[2]  + w[3]*in[3];
      float v1 = qb[c4*4+1] + w[4]*in[0]  + w[5]*in[1]  + w[6]*in[2]  + w[7]*in[3];
      float v2 = qb[c4*4+2] + w[8]*in[0]  + w[9]*in[1]  + w[10]*in[2] + w[11]*in[3];
      float v3 = qb[c4*4+3] + w[12]*in[0] + w[13]*in[1] + w[14]*in[2] + w[15]*in[3];
      uint2 pk; pk.x = pack2bf(v0, v1); pk.y = pack2bf(v2, v3);
      *(uint2*)(qbf + base) = pk;
    }
    {
      const float* w = kw + c4 * 16;
      float v0 = kb[c4*4+0] + w[0]*in[0]  + w[1]*in[1]  + w[2]*in[2]  + w[3]*in[3];
      float v1 = kb[c4*4+1] + w[4]*in[0]  + w[5]*in[1]  + w[6]*in[2]  + w[7]*in[3];
      float v2 = kb[c4*4+2] + w[8]*in[0]  + w[9]*in[1]  + w[10]*in[2] + w[11]*in[3];
      float v3 = kb[c4*4+3] + w[12]*in[0] + w[13]*in[1] + w[14]*in[2] + w[15]*in[3];
      uint2 pk; pk.x = pack2bf(v0, v1); pk.y = pack2bf(v2, v3);
      *(uint2*)(kbf + base) = pk;
    }
    {
      const float* w = vw + c4 * 16;
      float vv[4];
      #pragma unroll
      for(int o = 0; o < 4; o++){
        float v = vb[c4*4+o] + w[o*4]*am[0] + w[o*4+1]*am[1] + w[o*4+2]*am[2] + w[o*4+3]*am[3];
        vv[o] = v;
        vt[sl][c4l * 4 + o] = v;
      }
      uint2 pk; pk.x = pack2bf(vv[0], vv[1]); pk.y = pack2bf(vv[2], vv[3]);
      *(uint2*)(vbf + abase) = pk;            // flat [t][384] for gate GEMM
    }
  }
  __syncthreads();
  #pragma unroll
  for(int it = 0; it < 24; it++){
    const int f = it * 256 + tid;                    // 96 d * 64 sl
    const int d = f >> 6, sl = f & 63;
    vtbf[((long)bh * 96 + d) * 1024 + s0 + sl] = (short)f2bf(vt[sl][d]);
  }
}

// ---------------- K2c: gate GEMM  C[8192x8] = gi @ [wi;wf]^T  (MFMA 16x16x32) ----------------
__global__ __launch_bounds__(256) void k2c_gates(
    const short* __restrict__ qbf, const short* __restrict__ kbf, const short* __restrict__ vbf,
    const float* __restrict__ wi, const float* __restrict__ bi,
    const float* __restrict__ wf, const float* __restrict__ bff,
    float* __restrict__ itv, float* __restrict__ ftv)
{
  __shared__ short wg[8 * 1160];                      // 8 gate rows, padded stride (18.6 KB)
  const int tid = threadIdx.x;
  const int t0 = blockIdx.x * 64;
  #pragma unroll
  for(int i = 0; i < 9; i++){
    const int u = i * 256 + tid;                      // f32x4 units, 2304 = 8 rows * 288
    const int row = u / 288, col4 = u % 288;
    const float* src = ((row < 4) ? wi + row * 1152 : wf + (row - 4) * 1152) + col4 * 4;
    f32x4 v = *(const f32x4*)src;
    uint2 pk; pk.x = pack2bf(v[0], v[1]); pk.y = pack2bf(v[2], v[3]);
    *(uint2*)(&wg[row * 1160 + col4 * 4]) = pk;
  }
  __syncthreads();
  const int w = tid >> 6, lane = tid & 63, qg = lane >> 4, l16 = lane & 15;
  const int tw = t0 + w * 16;
  const int tA = tw + l16;
  const int b = tA >> 10, s = tA & 1023;
  f32x4 acc = (f32x4){0.f,0.f,0.f,0.f};
  #pragma unroll
  for(int kc = 0; kc < 36; kc++){
    const int blk = kc / 3;                           // 96-block 0..11 (compile-time)
    const int off = (kc % 3) * 32 + qg * 8;
    short8 af;
    if(blk < 4)      af = *(const short8*)(qbf + ((long)(b*4+blk)*1024 + s)*96 + off);
    else if(blk < 8) af = *(const short8*)(kbf + ((long)(b*4+blk-4)*1024 + s)*96 + off);
    else             af = *(const short8*)(vbf + (long)tA*384 + (blk-8)*96 + off);
    short8 bf8 = *(const short8*)(&wg[(l16 & 7) * 1160 + kc * 32 + qg * 8]);
    acc = __builtin_amdgcn_mfma_f32_16x16x32_bf16(af, bf8, acc, 0, 0, 0);
  }
  if(l16 < 8){
    const int gh = l16 & 3;
    const float bias = (l16 < 4) ? bi[gh] : bff[gh];
    float* dst = (l16 < 4) ? itv : ftv;
    #pragma unroll
    for(int r = 0; r < 4; r++){
      const int t = tw + 4 * qg + r;
      dst[((long)((t >> 10) * 4 + gh)) * 1024 + (t & 1023)] = acc[r] + bias;
    }
  }
}

// ---------------- K3: per (b,h) scan ----------------
__global__ __launch_bounds__(256) void k3_scan(
    const float* __restrict__ itv, const float* __restrict__ ftv,
    float* __restrict__ Ev, float* __restrict__ Rpv, float* __restrict__ dsv)
{
  __shared__ float sb[256];
  const int bh = blockIdx.x, tid = threadIdx.x;
  const long base = (long)bh * 1024 + tid * 4;
  f32x4 f4 = *(const f32x4*)(ftv + base);
  const float l0 = logsigf_(f4[0]);
  const float l1 = logsigf_(f4[1]);
  const float l2 = logsigf_(f4[2]);
  const float l3 = logsigf_(f4[3]);
  float c0 = l0, c1 = l0 + l1, c2 = c1 + l2, c3 = c2 + l3;
  sb[tid] = c3;
  __syncthreads();
  for(int off = 1; off < 256; off <<= 1){
    float mine = sb[tid];
    float oth = (tid >= off) ? sb[tid - off] : 0.f;
    __syncthreads();
    sb[tid] = mine + oth;
    __syncthreads();
  }
  const float excl = (tid > 0) ? sb[tid - 1] : 0.f;
  c0 += excl; c1 += excl; c2 += excl; c3 += excl;
  f32x4 i4 = *(const f32x4*)(itv + base);
  const float m0 = i4[0] - c0, m1 = i4[1] - c1, m2 = i4[2] - c2, m3 = i4[3] - c3;
  const float x1 = fmaxf(m0, m1), x2 = fmaxf(x1, m2), x3 = fmaxf(x2, m3);
  __syncthreads();
  sb[tid] = x3;
  __syncthreads();
  for(int off = 1; off < 256; off <<= 1){
    float mine = sb[tid];
    float oth = (tid >= off) ? sb[tid - off] : -3.4e38f;
    __syncthreads();
    sb[tid] = fmaxf(mine, oth);
    __syncthreads();
  }
  const float exm = (tid > 0) ? sb[tid - 1] : -3.4e38f;
  const float M0 = fmaxf(m0, exm);
  const float M1 = fmaxf(x1, exm);
  const float M2 = fmaxf(x2, exm);
  const float M3 = fmaxf(x3, exm);
  f32x4 e, rp, ds;
  e[0] = __expf(m0); e[1] = __expf(m1); e[2] = __expf(m2); e[3] = __expf(m3);
  rp[0] = __expf(-M0) * (1.f/TAU_); rp[1] = __expf(-M1) * (1.f/TAU_);
  rp[2] = __expf(-M2) * (1.f/TAU_); rp[3] = __expf(-M3) * (1.f/TAU_);
  ds[0] = __expf(-(c0 + M0)); ds[1] = __expf(-(c1 + M1));
  ds[2] = __expf(-(c2 + M2)); ds[3] = __expf(-(c3 + M3));
  *(f32x4*)(Ev  + base) = e;
  *(f32x4*)(Rpv + base) = rp;
  *(f32x4*)(dsv + base) = ds;
}

// ---------------- K4: flash mLSTM attention; prefetch-distance-2 register pipeline ----------------
__global__ __launch_bounds__(256, 2) void k4_attn(
    const short* __restrict__ qbf, const short* __restrict__ kbf, const short* __restrict__ vtbf,
    const float* __restrict__ Ev, const float* __restrict__ Rpv, const float* __restrict__ dsv,
    const float* __restrict__ gn_g, const float* __restrict__ gn_b,
    const unsigned short* __restrict__ qkbf, const unsigned short* __restrict__ bgate,
    const float* __restrict__ skip, short* __restrict__ o1bf)
{
  __shared__ short kbuf[2][64 * 104];
  __shared__ short vbuf[2][96 * 72];
  __shared__ float ebuf[2][64];
  __shared__ short P[4][16][72];
  const int tid = threadIdx.x;
  const int w = tid >> 6, lane = tid & 63, qg = lane >> 4, l16 = lane & 15;
  const int xcd = blockIdx.x & 7, q = blockIdx.x >> 3;
  const int bh = ((q & 3) << 3) | xcd;
  const int qh = q >> 2;
  const int ib = (q < 32) ? (15 - qh) : (qh - 8);
  const int i0w = ib * 64 + w * 16;
  const long qkbase = (long)bh * 1024;
  const int nj = ib + 1;

  short8 qf[3];
  #pragma unroll
  for(int kc = 0; kc < 3; kc++)
    qf[kc] = *(const short8*)(qbf + (qkbase + i0w + l16) * 96 + kc * 32 + 8 * qg);
  const float rp = Rpv[qkbase + i0w + l16];
  const float ds = dsv[qkbase + i0w + l16];

  f32x4 acc[6];
  #pragma unroll
  for(int dt = 0; dt < 6; dt++) acc[dt] = (f32x4){0.f,0.f,0.f,0.f};
  float bp = 0.f;

  const int rK0 = tid / 12,        cK0 = tid % 12;
  const int rK1 = (tid+256) / 12,  cK1 = (tid+256) % 12;
  const int rK2 = (tid+512) / 12,  cK2 = (tid+512) % 12;
  const int dV0 = tid >> 3,        cV0 = tid & 7;
  const int dV1 = (tid+256) >> 3,  cV1 = (tid+256) & 7;
  const int dV2 = (tid+512) >> 3,  cV2 = (tid+512) & 7;
  const bool he = (tid < 16);
  // two register stage-sets (A/B) for prefetch distance 2
  short8 skA0, skA1, skA2, svA0, svA1, svA2; f32x4 seA;
  short8 skB0, skB1, skB2, svB0, svB1, svB2; f32x4 seB;
  const short* kgb = kbf + qkbase * 96;
  const short* vgb = vtbf + (long)bh * 96 * 1024;

#define STAGE_LOAD(SET, J0)                                                \
  {                                                                        \
    const int j0_ = (J0);                                                  \
    sk##SET##0 = *(const short8*)(kgb + (j0_ + rK0) * 96 + cK0 * 8);       \
    sk##SET##1 = *(const short8*)(kgb + (j0_ + rK1) * 96 + cK1 * 8);       \
    sk##SET##2 = *(const short8*)(kgb + (j0_ + rK2) * 96 + cK2 * 8);       \
    sv##SET##0 = *(const short8*)(vgb + (long)dV0 * 1024 + j0_ + cV0 * 8); \
    sv##SET##1 = *(const short8*)(vgb + (long)dV1 * 1024 + j0_ + cV1 * 8); \
    sv##SET##2 = *(const short8*)(vgb + (long)dV2 * 1024 + j0_ + cV2 * 8); \
    if(he) se##SET = *(const f32x4*)(Ev + qkbase + j0_ + tid * 4);         \
  }

#define STAGE_WRITE(SET, B)                                     \
  {                                                             \
    *(short8*)(&kbuf[B][rK0 * 104 + cK0 * 8]) = sk##SET##0;     \
    *(short8*)(&kbuf[B][rK1 * 104 + cK1 * 8]) = sk##SET##1;     \
    *(short8*)(&kbuf[B][rK2 * 104 + cK2 * 8]) = sk##SET##2;     \
    *(short8*)(&vbuf[B][dV0 * 72 + cV0 * 8]) = sv##SET##0;      \
    *(short8*)(&vbuf[B][dV1 * 72 + cV1 * 8]) = sv##SET##1;      \
    *(short8*)(&vbuf[B][dV2 * 72 + cV2 * 8]) = sv##SET##2;      \
    if(he) *(f32x4*)(&ebuf[B][tid * 4]) = se##SET;              \
  }

#define COMPUTE(CUR, JT)                                                                   \
  {                                                                                        \
    const int j0_ = (JT) * 64;                                                             \
    const bool diag_ = ((JT) == nj - 1);                                                   \
    const int i_ = i0w + l16;                                                              \
    __builtin_amdgcn_s_setprio(1);                                                         \
    _Pragma("unroll")                                                                      \
    for(int jsub = 0; jsub < 4; jsub++){                                                   \
      f32x4 C = (f32x4){0.f,0.f,0.f,0.f};                                                  \
      _Pragma("unroll")                                                                    \
      for(int kc = 0; kc < 3; kc++){                                                       \
        short8 kf = *(const short8*)(&kbuf[CUR][(jsub*16 + l16) * 104 + kc * 32 + 8 * qg]);\
        C = __builtin_amdgcn_mfma_f32_16x16x32_bf16(kf, qf[kc], C, 0, 0, 0);               \
      }                                                                                    \
      f32x4 e4 = *(const f32x4*)(&ebuf[CUR][jsub * 16 + 4 * qg]);                          \
      float v0 = C[0] * e4[0];                                                             \
      float v1 = C[1] * e4[1];                                                             \
      float v2 = C[2] * e4[2];                                                             \
      float v3 = C[3] * e4[3];                                                             \
      if(diag_){                                                                           \
        const int jb = j0_ + jsub * 16 + 4 * qg;                                           \
        if(jb + 0 > i_) v0 = 0.f;                                                          \
        if(jb + 1 > i_) v1 = 0.f;                                                          \
        if(jb + 2 > i_) v2 = 0.f;                                                          \
        if(jb + 3 > i_) v3 = 0.f;                                                          \
      }                                                                                    \
      bp += v0 + v1 + v2 + v3;                                                             \
      uint2 pw; pw.x = pack2bf(v0, v1); pw.y = pack2bf(v2, v3);                            \
      *(uint2*)(&P[w][l16][jsub * 16 + 4 * qg]) = pw;                                      \
    }                                                                                      \
    asm volatile("s_waitcnt lgkmcnt(0)" ::: "memory");                                     \
    _Pragma("unroll")                                                                      \
    for(int ksub = 0; ksub < 2; ksub++){                                                   \
      short8 pa = *(const short8*)(&P[w][l16][ksub * 32 + 8 * qg]);                        \
      _Pragma("unroll")                                                                    \
      for(int dt = 0; dt < 6; dt++){                                                       \
        short8 vf = *(const short8*)(&vbuf[CUR][(dt * 16 + l16) * 72 + ksub * 32 + 8 * qg]);\
        acc[dt] = __builtin_amdgcn_mfma_f32_16x16x32_bf16(pa, vf, acc[dt], 0, 0, 0);       \
      }                                                                                    \
    }                                                                                      \
    __builtin_amdgcn_s_setprio(0);                                                         \
  }

  STAGE_LOAD(A, 0);
  if(nj > 1) STAGE_LOAD(B, 64);
  int cur = 0;
  #pragma unroll 1
  for(int jt = 0; jt < nj; jt += 2){
    STAGE_WRITE(A, cur);
    __syncthreads();
    if(jt + 2 < nj) STAGE_LOAD(A, (jt + 2) * 64);
    COMPUTE(cur, jt);
    cur ^= 1;
    if(jt + 1 < nj){
      STAGE_WRITE(B, cur);
      __syncthreads();
      if(jt + 3 < nj) STAGE_LOAD(B, (jt + 3) * 64);
      COMPUTE(cur, jt + 1);
      cur ^= 1;
    }
  }
#undef STAGE_LOAD
#undef STAGE_WRITE
#undef COMPUTE

  const int head = bh & 3, bb = bh >> 2;
  float bsum = bp;
  bsum += __shfl_xor(bsum, 16);
  bsum += __shfl_xor(bsum, 32);
  const float bfull = bsum * rp;
  const float den = fmaxf(fabsf(bfull), ds) + 1e-6f;
  const float sc = rp / den;
  float srow[4];
  #pragma unroll
  for(int r = 0; r < 4; r++) srow[r] = __shfl(sc, 4 * qg + r);
  float hv[6][4], mu[4], rs[4];
  #pragma unroll
  for(int r = 0; r < 4; r++){
    float sm = 0.f, sq = 0.f;
    #pragma unroll
    for(int dt = 0; dt < 6; dt++){
      const float h = acc[dt][r] * srow[r];
      hv[dt][r] = h; sm += h; sq += h * h;
    }
    sm += __shfl_xor(sm, 1); sm += __shfl_xor(sm, 2); sm += __shfl_xor(sm, 4); sm += __shfl_xor(sm, 8);
    sq += __shfl_xor(sq, 1); sq += __shfl_xor(sq, 2); sq += __shfl_xor(sq, 4); sq += __shfl_xor(sq, 8);
    const float m_ = sm * (1.f/96.f);
    mu[r] = m_;
    rs[r] = rsqrtf(sq * (1.f/96.f) - m_ * m_ + 1e-5f);
  }
  __syncthreads();
  short* hstage = &kbuf[0][0];
  #pragma unroll
  for(int dt = 0; dt < 6; dt++){
    const int col = head * 96 + dt * 16 + l16;
    const float g  = gn_g[col];
    const float be = gn_b[col];
    #pragma unroll
    for(int r = 0; r < 4; r++){
      const float hn = (hv[dt][r] - mu[r]) * rs[r] * g + be;
      hstage[(w * 16 + 4 * qg + r) * 104 + dt * 16 + l16] = (short)f2bf(hn);
    }
  }
  __syncthreads();
  #pragma unroll
  for(int u2 = 0; u2 < 3; u2++){
    const int f = u2 * 256 + tid;
    const int row = f / 12, c8 = f % 12;
    const long off = ((long)(bb * 1024 + ib * 64 + row)) * 384 + head * 96 + c8 * 8;
    short8 h8 = *(const short8*)(hstage + row * 104 + c8 * 8);
    short8 q8 = *(const short8*)((const short*)qkbf + off);
    short8 g8 = *(const short8*)((const short*)bgate + off);
    f32x4 s0 = *(const f32x4*)(skip + head * 96 + c8 * 8);
    f32x4 s1 = *(const f32x4*)(skip + head * 96 + c8 * 8 + 4);
    float o[8];
    #pragma unroll
    for(int i = 0; i < 8; i++){
      const float sk = (i < 4) ? s0[i] : s1[i - 4];
      o[i] = (bf2f((unsigned short)h8[i]) + sk * bf2f((unsigned short)q8[i]))
             * bf2f((unsigned short)g8[i]);
    }
    union { short8 s; unsigned u4[4]; } ov;
    ov.u4[0] = pack2bf(o[0], o[1]); ov.u4[1] = pack2bf(o[2], o[3]);
    ov.u4[2] = pack2bf(o[4], o[5]); ov.u4[3] = pack2bf(o[6], o[7]);
    *(short8*)(o1bf + off) = ov.s;
  }
}

// ---------------- K5: out = o1 @ wo^T + bo + x, M-tile 128, bf16 weights ----------------
__global__ __launch_bounds__(256) void k5_gemm(
    const short* __restrict__ o1bf, const short* __restrict__ wobf,
    const float* __restrict__ bo, const float* __restrict__ x, float* __restrict__ out)
{
  __shared__ short wt[18432];                          // 48*384 bf16 = 36864 B
  const int tid = threadIdx.x;
  const int ng = blockIdx.x & 3;
  const int t0 = (blockIdx.x >> 2) * 128;
  {
    const short* src = wobf + (long)ng * 48 * 384;
    #pragma unroll
    for(int i = 0; i < 9; i++){
      const int u = i * 256 + tid;                     // 16B units, 0..2303
      const int row = u / 48;
      const int dst = (u * 16) ^ ((row & 7) << 4);
      *(short8*)((char*)wt + dst) = *(const short8*)(src + u * 8);
    }
  }
  __syncthreads();
  const int widx = tid >> 6, lane = tid & 63, qg = lane >> 4, l16 = lane & 15;
  const int m0 = t0 + widx * 32;
  f32x4 acc[2][3];
  #pragma unroll
  for(int mt = 0; mt < 2; mt++)
    #pragma unroll
    for(int nt = 0; nt < 3; nt++) acc[mt][nt] = (f32x4){0.f,0.f,0.f,0.f};
  const short* arow0 = o1bf + (long)(m0 + l16) * 384;
  const short* arow1 = o1bf + (long)(m0 + 16 + l16) * 384;
  #pragma unroll
  for(int kc = 0; kc < 12; kc++){
    short8 af0 = *(const short8*)(arow0 + kc * 32 + 8 * qg);
    short8 af1 = *(const short8*)(arow1 + kc * 32 + 8 * qg);
    #pragma unroll
    for(int nt = 0; nt < 3; nt++){
      const int row = nt * 16 + l16;
      int byte = row * 768 + kc * 64 + qg * 16;
      byte ^= (row & 7) << 4;
      short8 bfr = *(const short8*)((const char*)wt + byte);
      acc[0][nt] = __builtin_amdgcn_mfma_f32_16x16x32_bf16(af0, bfr, acc[0][nt], 0, 0, 0);
      acc[1][nt] = __builtin_amdgcn_mfma_f32_16x16x32_bf16(af1, bfr, acc[1][nt], 0, 0, 0);
    }
  }
  #pragma unroll
  for(int mt = 0; mt < 2; mt++){
    #pragma unroll
    for(int nt = 0; nt < 3; nt++){
      const int n = ng * 48 + nt * 16 + l16;
      const float b_ = bo[n];
      #pragma unroll
      for(int r = 0; r < 4; r++){
        const int trow = m0 + mt * 16 + 4 * qg + r;
        out[(long)trow * 192 + n] = acc[mt][nt][r] + b_ + x[(long)trow * 192 + n];
      }
    }
  }
}

// ---------------- launch ----------------
extern "C" void kernel_launch(void* const* d_in, const int* in_sizes, int n_in,
                              void* d_out, int out_size, void* d_ws, size_t ws_size,
                              hipStream_t stream)
{
  (void)in_sizes; (void)n_in; (void)out_size; (void)ws_size;
  const float* x    = (const float*)d_in[0];
  const float* ln_g = (const float*)d_in[1];
  const float* ln_b = (const float*)d_in[2];
  const float* w1   = (const float*)d_in[3];
  const float* b1   = (const float*)d_in[4];
  const float* w2   = (const float*)d_in[5];
  const float* b2   = (const float*)d_in[6];
  const float* cw   = (const float*)d_in[7];
  const float* cb   = (const float*)d_in[8];
  const float* qw   = (const float*)d_in[9];
  const float* qb   = (const float*)d_in[10];
  const float* kw   = (const float*)d_in[11];
  const float* kb   = (const float*)d_in[12];
  const float* vw   = (const float*)d_in[13];
  const float* vb   = (const float*)d_in[14];
  const float* wi   = (const float*)d_in[15];
  const float* bi   = (const float*)d_in[16];
  const float* wf   = (const float*)d_in[17];
  const float* bff  = (const float*)d_in[18];
  const float* gn_g = (const float*)d_in[19];
  const float* gn_b = (const float*)d_in[20];
  const float* wo   = (const float*)d_in[21];
  const float* bo   = (const float*)d_in[22];
  const float* skip = (const float*)d_in[23];
  float* out = (float*)d_out;

  char* ws = (char*)d_ws;
  unsigned short* abf   = (unsigned short*)(ws + 0);           // 6.29 MB
  short* vbf   = (short*)(ws + 6291456);                       // 6.29 MB
  unsigned short* bgate = (unsigned short*)(ws + 12582912);
  unsigned short* qkbf  = (unsigned short*)(ws + 25165824);
  short* xnbf  = (short*)(ws + 37748736);                      // 3.15 MB
  short* w12bf = (short*)(ws + 40894464);                      // 295 KB
  short* wobf  = (short*)(ws + 41189376);                      // 147 KB
  short* o1bf  = (short*)(ws + 41943040);
  short* qbf   = (short*)(ws + 50331648);
  short* kbf   = (short*)(ws + 56623104);
  short* vtbf  = (short*)(ws + 62914560);
  float* itv   = (float*)(ws + 69648384);
  float* ftv   = (float*)(ws + 69779456);
  float* Ev    = (float*)(ws + 69910528);
  float* Rpv   = (float*)(ws + 70041600);
  float* dsv   = (float*)(ws + 70172672);

  k1a_ln<<<728, 256, 0, stream>>>(x, ln_g, ln_b, w1, w2, wo, xnbf, w12bf, wobf);
  k1b_gemm<<<512, 256, 0, stream>>>(xnbf, w12bf, b1, b2, abf, bgate);
  k2bv<<<512, 256, 0, stream>>>(abf, cw, cb, qw, qb, kw, kb, vw, vb, qkbf, qbf, kbf, vbf, vtbf);
  k2c_gates<<<128, 256, 0, stream>>>(qbf, kbf, vbf, wi, bi, wf, bff, itv, ftv);
  k3_scan<<<32, 256, 0, stream>>>(itv, ftv, Ev, Rpv, dsv);
  k4_attn<<<512, 256, 0, stream>>>(qbf, kbf, vtbf, Ev, Rpv, dsv, gn_g, gn_b,
                                   qkbf, bgate, skip, o1bf);
  k5_gemm<<<256, 256, 0, stream>>>(o1bf, wobf, bo, x, out);
}

// Round 17
// 78.808 us; speedup vs baseline: 1.0169x; 1.0169x over previous
//
#include <hip/hip_runtime.h>
#include <cstdint>

#define TAU_ 9.797958971132712f

typedef __attribute__((ext_vector_type(4))) float f32x4;
typedef __attribute__((ext_vector_type(8))) short short8;

#define DEV static __device__ __forceinline__

DEV unsigned short f2bf(float f){
  union { float f; unsigned u; } v; v.f = f;
  unsigned r = v.u + 0x7FFFu + ((v.u >> 16) & 1u);
  return (unsigned short)(r >> 16);
}
DEV float bf2f(unsigned short u){
  union { unsigned u; float f; } v; v.u = ((unsigned)u) << 16; return v.f;
}
DEV unsigned pack2bf(float a, float b){
  unsigned r;
  asm("v_cvt_pk_bf16_f32 %0, %1, %2" : "=v"(r) : "v"(a), "v"(b));
  return r;
}
DEV f32x4 ld_bf4(const unsigned short* p){
  uint2 r = *(const uint2*)p;
  f32x4 o;
  o[0] = bf2f((unsigned short)(r.x & 0xffff));
  o[1] = bf2f((unsigned short)(r.x >> 16));
  o[2] = bf2f((unsigned short)(r.y & 0xffff));
  o[3] = bf2f((unsigned short)(r.y >> 16));
  return o;
}
DEV float siluf_(float x){ return x / (1.f + __expf(-x)); }
DEV float logsigf_(float x){ return fminf(x, 0.f) - log1pf(__expf(-fabsf(x))); }

// ---------------- K1a: LayerNorm (blocks 0-511) + weight f32->bf16 convert (tail) ----------------
__global__ __launch_bounds__(256) void k1a_ln(
    const float* __restrict__ x, const float* __restrict__ ln_g, const float* __restrict__ ln_b,
    const float* __restrict__ w1, const float* __restrict__ w2, const float* __restrict__ wo,
    short* __restrict__ xnbf, short* __restrict__ w12bf, short* __restrict__ wobf)
{
  const int tid = threadIdx.x;
  if(blockIdx.x >= 512){
    const int idx4 = (blockIdx.x - 512) * 256 + tid;   // 216*256 = 55296 f32x4 units
    const float* src; short* dst; int off;
    if(idx4 < 18432)      { src = w1; dst = w12bf;         off = idx4; }
    else if(idx4 < 36864) { src = w2; dst = w12bf + 73728; off = idx4 - 18432; }
    else                  { src = wo; dst = wobf;          off = idx4 - 36864; }
    f32x4 v = *(const f32x4*)(src + off * 4);
    uint2 pk; pk.x = pack2bf(v[0], v[1]); pk.y = pack2bf(v[2], v[3]);
    *(uint2*)(dst + off * 4) = pk;
    return;
  }
  const int t = blockIdx.x * 16 + (tid >> 4);
  const int g = tid & 15;
  const float* xr = x + (long)t * 192 + g * 12;
  f32x4 v0 = *(const f32x4*)(xr);
  f32x4 v1 = *(const f32x4*)(xr + 4);
  f32x4 v2 = *(const f32x4*)(xr + 8);
  float s  = v0[0]+v0[1]+v0[2]+v0[3] + v1[0]+v1[1]+v1[2]+v1[3] + v2[0]+v2[1]+v2[2]+v2[3];
  float sq = v0[0]*v0[0]+v0[1]*v0[1]+v0[2]*v0[2]+v0[3]*v0[3]
           + v1[0]*v1[0]+v1[1]*v1[1]+v1[2]*v1[2]+v1[3]*v1[3]
           + v2[0]*v2[0]+v2[1]*v2[1]+v2[2]*v2[2]+v2[3]*v2[3];
  s  += __shfl_xor(s, 1);  s  += __shfl_xor(s, 2);  s  += __shfl_xor(s, 4);  s  += __shfl_xor(s, 8);
  sq += __shfl_xor(sq, 1); sq += __shfl_xor(sq, 2); sq += __shfl_xor(sq, 4); sq += __shfl_xor(sq, 8);
  const float mean = s * (1.f/192.f);
  const float rstd = rsqrtf(sq * (1.f/192.f) - mean * mean + 1e-5f);
  const int c0 = g * 12;
  f32x4 g0 = *(const f32x4*)(ln_g + c0),     b0 = *(const f32x4*)(ln_b + c0);
  f32x4 g1 = *(const f32x4*)(ln_g + c0 + 4), b1 = *(const f32x4*)(ln_b + c0 + 4);
  f32x4 g2 = *(const f32x4*)(ln_g + c0 + 8), b2 = *(const f32x4*)(ln_b + c0 + 8);
  unsigned pk[6];
  pk[0] = pack2bf((v0[0]-mean)*rstd*g0[0]+b0[0], (v0[1]-mean)*rstd*g0[1]+b0[1]);
  pk[1] = pack2bf((v0[2]-mean)*rstd*g0[2]+b0[2], (v0[3]-mean)*rstd*g0[3]+b0[3]);
  pk[2] = pack2bf((v1[0]-mean)*rstd*g1[0]+b1[0], (v1[1]-mean)*rstd*g1[1]+b1[1]);
  pk[3] = pack2bf((v1[2]-mean)*rstd*g1[2]+b1[2], (v1[3]-mean)*rstd*g1[3]+b1[3]);
  pk[4] = pack2bf((v2[0]-mean)*rstd*g2[0]+b2[0], (v2[1]-mean)*rstd*g2[1]+b2[1]);
  pk[5] = pack2bf((v2[2]-mean)*rstd*g2[2]+b2[2], (v2[3]-mean)*rstd*g2[3]+b2[3]);
  uint2* xo = (uint2*)(xnbf + (long)t * 192 + g * 12);
  xo[0] = make_uint2(pk[0], pk[1]);
  xo[1] = make_uint2(pk[2], pk[3]);
  xo[2] = make_uint2(pk[4], pk[5]);
}

// ---------------- K1b: dual GEMM, M-tile 128, bf16 weights ----------------
__global__ __launch_bounds__(256) void k1b_gemm(
    const short* __restrict__ xnbf, const short* __restrict__ w12bf,
    const float* __restrict__ b1, const float* __restrict__ b2,
    unsigned short* __restrict__ abf, unsigned short* __restrict__ bgate)
{
  __shared__ short wt[18432];                          // 96*192 bf16 = 36.9 KB
  const int tid = threadIdx.x;
  const int ntg = blockIdx.x & 7;
  const int t0 = (blockIdx.x >> 3) * 128;
  {
    const short* src = w12bf + (long)ntg * 96 * 192;
    #pragma unroll
    for(int i = 0; i < 9; i++){
      const int u = i * 256 + tid;                     // 16B unit, 0..2303
      const int row = u / 24;
      const int dst = (u * 16) ^ ((row & 7) << 4);
      *(short8*)((char*)wt + dst) = *(const short8*)(src + u * 8);
    }
  }
  __syncthreads();
  const int widx = tid >> 6, lane = tid & 63, qg = lane >> 4, l16 = lane & 15;
  const int m0 = t0 + widx * 32;
  f32x4 acc[2][6];
  #pragma unroll
  for(int mt = 0; mt < 2; mt++)
    #pragma unroll
    for(int nt = 0; nt < 6; nt++) acc[mt][nt] = (f32x4){0.f,0.f,0.f,0.f};
  const short* xrow0 = xnbf + (long)(m0 + l16) * 192;
  const short* xrow1 = xnbf + (long)(m0 + 16 + l16) * 192;
  #pragma unroll
  for(int kc = 0; kc < 6; kc++){
    short8 af0 = *(const short8*)(xrow0 + kc * 32 + 8 * qg);
    short8 af1 = *(const short8*)(xrow1 + kc * 32 + 8 * qg);
    #pragma unroll
    for(int nt = 0; nt < 6; nt++){
      const int row = nt * 16 + l16;
      int byte = row * 384 + (kc * 32 + 8 * qg) * 2;
      byte ^= (row & 7) << 4;
      short8 bfr = *(const short8*)((const char*)wt + byte);
      acc[0][nt] = __builtin_amdgcn_mfma_f32_16x16x32_bf16(af0, bfr, acc[0][nt], 0, 0, 0);
      acc[1][nt] = __builtin_amdgcn_mfma_f32_16x16x32_bf16(af1, bfr, acc[1][nt], 0, 0, 0);
    }
  }
  const int half = ntg >> 2;
  const float* bias = half ? b2 : b1;
  const int ncol = (ntg & 3) * 96;
  #pragma unroll
  for(int mt = 0; mt < 2; mt++){
    #pragma unroll
    for(int nt = 0; nt < 6; nt++){
      const int n = ncol + nt * 16 + l16;
      const float bs = bias[n];
      #pragma unroll
      for(int r = 0; r < 4; r++){
        const int trow = m0 + mt * 16 + 4 * qg + r;
        float v = acc[mt][nt][r] + bs;
        if(half) bgate[(long)trow * 384 + n] = f2bf(siluf_(v));
        else     abf[(long)trow * 384 + n] = f2bf(v);
      }
    }
  }
}

// ---------------- K2bv: dwconv+silu -> qkbuf bf16, q/k proj -> bf16, v -> vbf + vtbf^T ----
__global__ __launch_bounds__(256) void k2bv(
    const unsigned short* __restrict__ abf,
    const float* __restrict__ cw, const float* __restrict__ cb,
    const float* __restrict__ qw, const float* __restrict__ qb,
    const float* __restrict__ kw, const float* __restrict__ kb,
    const float* __restrict__ vw, const float* __restrict__ vb,
    unsigned short* __restrict__ qkbf, short* __restrict__ qbf, short* __restrict__ kbf,
    short* __restrict__ vbf, short* __restrict__ vtbf)
{
  __shared__ float vt[64][97];
  const int tid = threadIdx.x;
  const int bh = blockIdx.x >> 4;
  const int b = bh >> 2, h = bh & 3;
  const int s0 = (blockIdx.x & 15) << 6;
  #pragma unroll
  for(int it = 0; it < 6; it++){
    const int f = it * 256 + tid;                     // 64 sl * 24 c4l
    const int sl = f / 24, c4l = f % 24;
    const int c4 = h * 24 + c4l;
    const int s = s0 + sl;
    const long t = (long)b * 1024 + s;
    const long abase = t * 384 + c4 * 4;
    f32x4 am = ld_bf4(abf + abase);
    f32x4 al = (s > 0)    ? ld_bf4(abf + abase - 384) : (f32x4){0.f,0.f,0.f,0.f};
    f32x4 ar = (s < 1023) ? ld_bf4(abf + abase + 384) : (f32x4){0.f,0.f,0.f,0.f};
    f32x4 cw0 = *(const f32x4*)(cw + c4 * 12);
    f32x4 cw1 = *(const f32x4*)(cw + c4 * 12 + 4);
    f32x4 cw2 = *(const f32x4*)(cw + c4 * 12 + 8);
    f32x4 cb4 = *(const f32x4*)(cb + c4 * 4);
    f32x4 in;
    in[0] = siluf_(cb4[0] + al[0]*cw0[0] + am[0]*cw0[1] + ar[0]*cw0[2]);
    in[1] = siluf_(cb4[1] + al[1]*cw0[3] + am[1]*cw1[0] + ar[1]*cw1[1]);
    in[2] = siluf_(cb4[2] + al[2]*cw1[2] + am[2]*cw1[3] + ar[2]*cw2[0]);
    in[3] = siluf_(cb4[3] + al[3]*cw2[1] + am[3]*cw2[2] + ar[3]*cw2[3]);
    {
      uint2 pk; pk.x = pack2bf(in[0], in[1]); pk.y = pack2bf(in[2], in[3]);
      *(uint2*)(qkbf + abase) = pk;
    }
    const long base = ((long)(b * 4 + h) * 1024 + s) * 96 + c4l * 4;
    {
      const float* w = qw + c4 * 16;
      float v0 = qb[c4*4+0] + w[0]*in[0]  + w[1]*in[1]  + w[2]*in[2]  + w[3]*in[3];
      float v1 = qb[c4*4+1] + w[4]*in[0]  + w[5]*in[1]  + w[6]*in[2]  + w[7]*in[3];
      float v2 = qb[c4*4+2] + w[8]*in[0]  + w[9]*in[1]  + w[10]*in[2] + w[11]*in[3];
      float v3 = qb[c4*4+3] + w[12]*in[0] + w[13]*in[1] + w[14]*in[2] + w[15]*in[3];
      uint2 pk; pk.x = pack2bf(v0, v1); pk.y = pack2bf(v2, v3);
      *(uint2*)(qbf + base) = pk;
    }
    {
      const float* w = kw + c4 * 16;
      float v0 = kb[c4*4+0] + w[0]*in[0]  + w[1]*in[1]  + w[2]*in[2]  + w[3]*in[3];
      float v1 = kb[c4*4+1] + w[4]*in[0]  + w[5]*in[1]  + w[6]*in[2]  + w[7]*in[3];
      float v2 = kb[c4*4+2] + w[8]*in[0]  + w[9]*in[1]  + w[10]*in[2] + w[11]*in[3];
      float v3 = kb[c4*4+3] + w[12]*in[0] + w[13]*in[1] + w[14]*in[2] + w[15]*in[3];
      uint2 pk; pk.x = pack2bf(v0, v1); pk.y = pack2bf(v2, v3);
      *(uint2*)(kbf + base) = pk;
    }
    {
      const float* w = vw + c4 * 16;
      float vv[4];
      #pragma unroll
      for(int o = 0; o < 4; o++){
        float v = vb[c4*4+o] + w[o*4]*am[0] + w[o*4+1]*am[1] + w[o*4+2]*am[2] + w[o*4+3]*am[3];
        vv[o] = v;
        vt[sl][c4l * 4 + o] = v;
      }
      uint2 pk; pk.x = pack2bf(vv[0], vv[1]); pk.y = pack2bf(vv[2], vv[3]);
      *(uint2*)(vbf + abase) = pk;            // flat [t][384] for gate GEMM
    }
  }
  __syncthreads();
  #pragma unroll
  for(int it = 0; it < 24; it++){
    const int f = it * 256 + tid;                    // 96 d * 64 sl
    const int d = f >> 6, sl = f & 63;
    vtbf[((long)bh * 96 + d) * 1024 + s0 + sl] = (short)f2bf(vt[sl][d]);
  }
}

// ---------------- K2c: gate GEMM  C[8192x8] = gi @ [wi;wf]^T  (MFMA 16x16x32) ----------------
__global__ __launch_bounds__(256) void k2c_gates(
    const short* __restrict__ qbf, const short* __restrict__ kbf, const short* __restrict__ vbf,
    const float* __restrict__ wi, const float* __restrict__ bi,
    const float* __restrict__ wf, const float* __restrict__ bff,
    float* __restrict__ itv, float* __restrict__ ftv)
{
  __shared__ short wg[8 * 1160];                      // 8 gate rows, padded stride (18.6 KB)
  const int tid = threadIdx.x;
  const int t0 = blockIdx.x * 64;
  #pragma unroll
  for(int i = 0; i < 9; i++){
    const int u = i * 256 + tid;                      // f32x4 units, 2304 = 8 rows * 288
    const int row = u / 288, col4 = u % 288;
    const float* src = ((row < 4) ? wi + row * 1152 : wf + (row - 4) * 1152) + col4 * 4;
    f32x4 v = *(const f32x4*)src;
    uint2 pk; pk.x = pack2bf(v[0], v[1]); pk.y = pack2bf(v[2], v[3]);
    *(uint2*)(&wg[row * 1160 + col4 * 4]) = pk;
  }
  __syncthreads();
  const int w = tid >> 6, lane = tid & 63, qg = lane >> 4, l16 = lane & 15;
  const int tw = t0 + w * 16;
  const int tA = tw + l16;
  const int b = tA >> 10, s = tA & 1023;
  f32x4 acc = (f32x4){0.f,0.f,0.f,0.f};
  #pragma unroll
  for(int kc = 0; kc < 36; kc++){
    const int blk = kc / 3;                           // 96-block 0..11 (compile-time)
    const int off = (kc % 3) * 32 + qg * 8;
    short8 af;
    if(blk < 4)      af = *(const short8*)(qbf + ((long)(b*4+blk)*1024 + s)*96 + off);
    else if(blk < 8) af = *(const short8*)(kbf + ((long)(b*4+blk-4)*1024 + s)*96 + off);
    else             af = *(const short8*)(vbf + (long)tA*384 + (blk-8)*96 + off);
    short8 bf8 = *(const short8*)(&wg[(l16 & 7) * 1160 + kc * 32 + qg * 8]);
    acc = __builtin_amdgcn_mfma_f32_16x16x32_bf16(af, bf8, acc, 0, 0, 0);
  }
  if(l16 < 8){
    const int gh = l16 & 3;
    const float bias = (l16 < 4) ? bi[gh] : bff[gh];
    float* dst = (l16 < 4) ? itv : ftv;
    #pragma unroll
    for(int r = 0; r < 4; r++){
      const int t = tw + 4 * qg + r;
      dst[((long)((t >> 10) * 4 + gh)) * 1024 + (t & 1023)] = acc[r] + bias;
    }
  }
}

// ---------------- K3: per (b,h) scan ----------------
__global__ __launch_bounds__(256) void k3_scan(
    const float* __restrict__ itv, const float* __restrict__ ftv,
    float* __restrict__ Ev, float* __restrict__ Rpv, float* __restrict__ dsv)
{
  __shared__ float sb[256];
  const int bh = blockIdx.x, tid = threadIdx.x;
  const long base = (long)bh * 1024 + tid * 4;
  f32x4 f4 = *(const f32x4*)(ftv + base);
  const float l0 = logsigf_(f4[0]);
  const float l1 = logsigf_(f4[1]);
  const float l2 = logsigf_(f4[2]);
  const float l3 = logsigf_(f4[3]);
  float c0 = l0, c1 = l0 + l1, c2 = c1 + l2, c3 = c2 + l3;
  sb[tid] = c3;
  __syncthreads();
  for(int off = 1; off < 256; off <<= 1){
    float mine = sb[tid];
    float oth = (tid >= off) ? sb[tid - off] : 0.f;
    __syncthreads();
    sb[tid] = mine + oth;
    __syncthreads();
  }
  const float excl = (tid > 0) ? sb[tid - 1] : 0.f;
  c0 += excl; c1 += excl; c2 += excl; c3 += excl;
  f32x4 i4 = *(const f32x4*)(itv + base);
  const float m0 = i4[0] - c0, m1 = i4[1] - c1, m2 = i4[2] - c2, m3 = i4[3] - c3;
  const float x1 = fmaxf(m0, m1), x2 = fmaxf(x1, m2), x3 = fmaxf(x2, m3);
  __syncthreads();
  sb[tid] = x3;
  __syncthreads();
  for(int off = 1; off < 256; off <<= 1){
    float mine = sb[tid];
    float oth = (tid >= off) ? sb[tid - off] : -3.4e38f;
    __syncthreads();
    sb[tid] = fmaxf(mine, oth);
    __syncthreads();
  }
  const float exm = (tid > 0) ? sb[tid - 1] : -3.4e38f;
  const float M0 = fmaxf(m0, exm);
  const float M1 = fmaxf(x1, exm);
  const float M2 = fmaxf(x2, exm);
  const float M3 = fmaxf(x3, exm);
  f32x4 e, rp, ds;
  e[0] = __expf(m0); e[1] = __expf(m1); e[2] = __expf(m2); e[3] = __expf(m3);
  rp[0] = __expf(-M0) * (1.f/TAU_); rp[1] = __expf(-M1) * (1.f/TAU_);
  rp[2] = __expf(-M2) * (1.f/TAU_); rp[3] = __expf(-M3) * (1.f/TAU_);
  ds[0] = __expf(-(c0 + M0)); ds[1] = __expf(-(c1 + M1));
  ds[2] = __expf(-(c2 + M2)); ds[3] = __expf(-(c3 + M3));
  *(f32x4*)(Ev  + base) = e;
  *(f32x4*)(Rpv + base) = rp;
  *(f32x4*)(dsv + base) = ds;
}

// ---------------- K4: flash mLSTM attention (R15 loop) + hoisted epilogue loads ----------------
__global__ __launch_bounds__(256, 2) void k4_attn(
    const short* __restrict__ qbf, const short* __restrict__ kbf, const short* __restrict__ vtbf,
    const float* __restrict__ Ev, const float* __restrict__ Rpv, const float* __restrict__ dsv,
    const float* __restrict__ gn_g, const float* __restrict__ gn_b,
    const unsigned short* __restrict__ qkbf, const unsigned short* __restrict__ bgate,
    const float* __restrict__ skip, short* __restrict__ o1bf)
{
  __shared__ short kbuf[2][64 * 104];
  __shared__ short vbuf[2][96 * 72];
  __shared__ float ebuf[2][64];
  __shared__ short P[4][16][72];
  const int tid = threadIdx.x;
  const int w = tid >> 6, lane = tid & 63, qg = lane >> 4, l16 = lane & 15;
  const int xcd = blockIdx.x & 7, q = blockIdx.x >> 3;
  const int bh = ((q & 3) << 3) | xcd;
  const int qh = q >> 2;
  const int ib = (q < 32) ? (15 - qh) : (qh - 8);
  const int i0w = ib * 64 + w * 16;
  const long qkbase = (long)bh * 1024;
  const int nj = ib + 1;

  short8 qf[3];
  #pragma unroll
  for(int kc = 0; kc < 3; kc++)
    qf[kc] = *(const short8*)(qbf + (qkbase + i0w + l16) * 96 + kc * 32 + 8 * qg);
  const float rp = Rpv[qkbase + i0w + l16];
  const float ds = dsv[qkbase + i0w + l16];

  f32x4 acc[6];
  #pragma unroll
  for(int dt = 0; dt < 6; dt++) acc[dt] = (f32x4){0.f,0.f,0.f,0.f};
  float bp = 0.f;

  const int rK0 = tid / 12,        cK0 = tid % 12;
  const int rK1 = (tid+256) / 12,  cK1 = (tid+256) % 12;
  const int rK2 = (tid+512) / 12,  cK2 = (tid+512) % 12;
  const int dV0 = tid >> 3,        cV0 = tid & 7;
  const int dV1 = (tid+256) >> 3,  cV1 = (tid+256) & 7;
  const int dV2 = (tid+512) >> 3,  cV2 = (tid+512) & 7;
  const bool he = (tid < 16);
  short8 sk0, sk1, sk2, sv0, sv1, sv2; f32x4 se;
  const short* kgb = kbf + qkbase * 96;
  const short* vgb = vtbf + (long)bh * 96 * 1024;

#define STAGE_LOAD(J0)                                              \
  {                                                                 \
    const int j0_ = (J0);                                           \
    sk0 = *(const short8*)(kgb + (j0_ + rK0) * 96 + cK0 * 8);       \
    sk1 = *(const short8*)(kgb + (j0_ + rK1) * 96 + cK1 * 8);       \
    sk2 = *(const short8*)(kgb + (j0_ + rK2) * 96 + cK2 * 8);       \
    sv0 = *(const short8*)(vgb + (long)dV0 * 1024 + j0_ + cV0 * 8); \
    sv1 = *(const short8*)(vgb + (long)dV1 * 1024 + j0_ + cV1 * 8); \
    sv2 = *(const short8*)(vgb + (long)dV2 * 1024 + j0_ + cV2 * 8); \
    if(he) se = *(const f32x4*)(Ev + qkbase + j0_ + tid * 4);       \
  }

#define STAGE_WRITE(B)                                   \
  {                                                      \
    *(short8*)(&kbuf[B][rK0 * 104 + cK0 * 8]) = sk0;     \
    *(short8*)(&kbuf[B][rK1 * 104 + cK1 * 8]) = sk1;     \
    *(short8*)(&kbuf[B][rK2 * 104 + cK2 * 8]) = sk2;     \
    *(short8*)(&vbuf[B][dV0 * 72 + cV0 * 8]) = sv0;      \
    *(short8*)(&vbuf[B][dV1 * 72 + cV1 * 8]) = sv1;      \
    *(short8*)(&vbuf[B][dV2 * 72 + cV2 * 8]) = sv2;      \
    if(he) *(f32x4*)(&ebuf[B][tid * 4]) = se;            \
  }

  STAGE_LOAD(0);
  int cur = 0;
  for(int jt = 0; jt < nj; jt++){
    STAGE_WRITE(cur);
    __syncthreads();
    if(jt + 1 < nj) STAGE_LOAD((jt + 1) * 64);

    const int j0 = jt * 64;
    const bool diag = (jt == nj - 1);
    const int i = i0w + l16;
    __builtin_amdgcn_s_setprio(1);
    #pragma unroll
    for(int jsub = 0; jsub < 4; jsub++){
      f32x4 C = (f32x4){0.f,0.f,0.f,0.f};
      #pragma unroll
      for(int kc = 0; kc < 3; kc++){
        short8 kf = *(const short8*)(&kbuf[cur][(jsub*16 + l16) * 104 + kc * 32 + 8 * qg]);
        C = __builtin_amdgcn_mfma_f32_16x16x32_bf16(kf, qf[kc], C, 0, 0, 0);
      }
      f32x4 e4 = *(const f32x4*)(&ebuf[cur][jsub * 16 + 4 * qg]);
      float v0 = C[0] * e4[0];
      float v1 = C[1] * e4[1];
      float v2 = C[2] * e4[2];
      float v3 = C[3] * e4[3];
      if(diag){
        const int jb = j0 + jsub * 16 + 4 * qg;
        if(jb + 0 > i) v0 = 0.f;
        if(jb + 1 > i) v1 = 0.f;
        if(jb + 2 > i) v2 = 0.f;
        if(jb + 3 > i) v3 = 0.f;
      }
      bp += v0 + v1 + v2 + v3;
      uint2 pw; pw.x = pack2bf(v0, v1); pw.y = pack2bf(v2, v3);
      *(uint2*)(&P[w][l16][jsub * 16 + 4 * qg]) = pw;
    }
    asm volatile("s_waitcnt lgkmcnt(0)" ::: "memory");
    #pragma unroll
    for(int ksub = 0; ksub < 2; ksub++){
      short8 pa = *(const short8*)(&P[w][l16][ksub * 32 + 8 * qg]);
      #pragma unroll
      for(int dt = 0; dt < 6; dt++){
        short8 vf = *(const short8*)(&vbuf[cur][(dt * 16 + l16) * 72 + ksub * 32 + 8 * qg]);
        acc[dt] = __builtin_amdgcn_mfma_f32_16x16x32_bf16(pa, vf, acc[dt], 0, 0, 0);
      }
    }
    __builtin_amdgcn_s_setprio(0);
    cur ^= 1;
  }
#undef STAGE_LOAD
#undef STAGE_WRITE

  // ---- T14: issue epilogue global loads NOW; consume after GN math ----
  const int head = bh & 3, bb = bh >> 2;
  short8 q8v[3], g8v[3];
  f32x4 s0v[3], s1v[3];
  long offv[3];
  #pragma unroll
  for(int u2 = 0; u2 < 3; u2++){
    const int f = u2 * 256 + tid;
    const int row = f / 12, c8 = f % 12;
    const long off = ((long)(bb * 1024 + ib * 64 + row)) * 384 + head * 96 + c8 * 8;
    offv[u2] = off;
    q8v[u2] = *(const short8*)((const short*)qkbf + off);
    g8v[u2] = *(const short8*)((const short*)bgate + off);
    s0v[u2] = *(const f32x4*)(skip + head * 96 + c8 * 8);
    s1v[u2] = *(const f32x4*)(skip + head * 96 + c8 * 8 + 4);
  }

  float bsum = bp;
  bsum += __shfl_xor(bsum, 16);
  bsum += __shfl_xor(bsum, 32);
  const float bfull = bsum * rp;
  const float den = fmaxf(fabsf(bfull), ds) + 1e-6f;
  const float sc = rp / den;
  float srow[4];
  #pragma unroll
  for(int r = 0; r < 4; r++) srow[r] = __shfl(sc, 4 * qg + r);
  float hv[6][4], mu[4], rs[4];
  #pragma unroll
  for(int r = 0; r < 4; r++){
    float sm = 0.f, sq = 0.f;
    #pragma unroll
    for(int dt = 0; dt < 6; dt++){
      const float h = acc[dt][r] * srow[r];
      hv[dt][r] = h; sm += h; sq += h * h;
    }
    sm += __shfl_xor(sm, 1); sm += __shfl_xor(sm, 2); sm += __shfl_xor(sm, 4); sm += __shfl_xor(sm, 8);
    sq += __shfl_xor(sq, 1); sq += __shfl_xor(sq, 2); sq += __shfl_xor(sq, 4); sq += __shfl_xor(sq, 8);
    const float m_ = sm * (1.f/96.f);
    mu[r] = m_;
    rs[r] = rsqrtf(sq * (1.f/96.f) - m_ * m_ + 1e-5f);
  }
  __syncthreads();
  short* hstage = &kbuf[0][0];
  #pragma unroll
  for(int dt = 0; dt < 6; dt++){
    const int col = head * 96 + dt * 16 + l16;
    const float g  = gn_g[col];
    const float be = gn_b[col];
    #pragma unroll
    for(int r = 0; r < 4; r++){
      const float hn = (hv[dt][r] - mu[r]) * rs[r] * g + be;
      hstage[(w * 16 + 4 * qg + r) * 104 + dt * 16 + l16] = (short)f2bf(hn);
    }
  }
  __syncthreads();
  #pragma unroll
  for(int u2 = 0; u2 < 3; u2++){
    const int f = u2 * 256 + tid;
    const int row = f / 12, c8 = f % 12;
    short8 h8 = *(const short8*)(hstage + row * 104 + c8 * 8);
    short8 q8 = q8v[u2];
    short8 g8 = g8v[u2];
    float o[8];
    #pragma unroll
    for(int i = 0; i < 8; i++){
      const float sk = (i < 4) ? s0v[u2][i] : s1v[u2][i - 4];
      o[i] = (bf2f((unsigned short)h8[i]) + sk * bf2f((unsigned short)q8[i]))
             * bf2f((unsigned short)g8[i]);
    }
    union { short8 s; unsigned u4[4]; } ov;
    ov.u4[0] = pack2bf(o[0], o[1]); ov.u4[1] = pack2bf(o[2], o[3]);
    ov.u4[2] = pack2bf(o[4], o[5]); ov.u4[3] = pack2bf(o[6], o[7]);
    *(short8*)(o1bf + offv[u2]) = ov.s;
  }
}

// ---------------- K5: out = o1 @ wo^T + bo + x, M-tile 128, bf16 weights ----------------
__global__ __launch_bounds__(256) void k5_gemm(
    const short* __restrict__ o1bf, const short* __restrict__ wobf,
    const float* __restrict__ bo, const float* __restrict__ x, float* __restrict__ out)
{
  __shared__ short wt[18432];                          // 48*384 bf16 = 36864 B
  const int tid = threadIdx.x;
  const int ng = blockIdx.x & 3;
  const int t0 = (blockIdx.x >> 2) * 128;
  {
    const short* src = wobf + (long)ng * 48 * 384;
    #pragma unroll
    for(int i = 0; i < 9; i++){
      const int u = i * 256 + tid;                     // 16B units, 0..2303
      const int row = u / 48;
      const int dst = (u * 16) ^ ((row & 7) << 4);
      *(short8*)((char*)wt + dst) = *(const short8*)(src + u * 8);
    }
  }
  __syncthreads();
  const int widx = tid >> 6, lane = tid & 63, qg = lane >> 4, l16 = lane & 15;
  const int m0 = t0 + widx * 32;
  f32x4 acc[2][3];
  #pragma unroll
  for(int mt = 0; mt < 2; mt++)
    #pragma unroll
    for(int nt = 0; nt < 3; nt++) acc[mt][nt] = (f32x4){0.f,0.f,0.f,0.f};
  const short* arow0 = o1bf + (long)(m0 + l16) * 384;
  const short* arow1 = o1bf + (long)(m0 + 16 + l16) * 384;
  #pragma unroll
  for(int kc = 0; kc < 12; kc++){
    short8 af0 = *(const short8*)(arow0 + kc * 32 + 8 * qg);
    short8 af1 = *(const short8*)(arow1 + kc * 32 + 8 * qg);
    #pragma unroll
    for(int nt = 0; nt < 3; nt++){
      const int row = nt * 16 + l16;
      int byte = row * 768 + kc * 64 + qg * 16;
      byte ^= (row & 7) << 4;
      short8 bfr = *(const short8*)((const char*)wt + byte);
      acc[0][nt] = __builtin_amdgcn_mfma_f32_16x16x32_bf16(af0, bfr, acc[0][nt], 0, 0, 0);
      acc[1][nt] = __builtin_amdgcn_mfma_f32_16x16x32_bf16(af1, bfr, acc[1][nt], 0, 0, 0);
    }
  }
  #pragma unroll
  for(int mt = 0; mt < 2; mt++){
    #pragma unroll
    for(int nt = 0; nt < 3; nt++){
      const int n = ng * 48 + nt * 16 + l16;
      const float b_ = bo[n];
      #pragma unroll
      for(int r = 0; r < 4; r++){
        const int trow = m0 + mt * 16 + 4 * qg + r;
        out[(long)trow * 192 + n] = acc[mt][nt][r] + b_ + x[(long)trow * 192 + n];
      }
    }
  }
}

// ---------------- launch ----------------
extern "C" void kernel_launch(void* const* d_in, const int* in_sizes, int n_in,
                              void* d_out, int out_size, void* d_ws, size_t ws_size,
                              hipStream_t stream)
{
  (void)in_sizes; (void)n_in; (void)out_size; (void)ws_size;
  const float* x    = (const float*)d_in[0];
  const float* ln_g = (const float*)d_in[1];
  const float* ln_b = (const float*)d_in[2];
  const float* w1   = (const float*)d_in[3];
  const float* b1   = (const float*)d_in[4];
  const float* w2   = (const float*)d_in[5];
  const float* b2   = (const float*)d_in[6];
  const float* cw   = (const float*)d_in[7];
  const float* cb   = (const float*)d_in[8];
  const float* qw   = (const float*)d_in[9];
  const float* qb   = (const float*)d_in[10];
  const float* kw   = (const float*)d_in[11];
  const float* kb   = (const float*)d_in[12];
  const float* vw   = (const float*)d_in[13];
  const float* vb   = (const float*)d_in[14];
  const float* wi   = (const float*)d_in[15];
  const float* bi   = (const float*)d_in[16];
  const float* wf   = (const float*)d_in[17];
  const float* bff  = (const float*)d_in[18];
  const float* gn_g = (const float*)d_in[19];
  const float* gn_b = (const float*)d_in[20];
  const float* wo   = (const float*)d_in[21];
  const float* bo   = (const float*)d_in[22];
  const float* skip = (const float*)d_in[23];
  float* out = (float*)d_out;

  char* ws = (char*)d_ws;
  unsigned short* abf   = (unsigned short*)(ws + 0);           // 6.29 MB
  short* vbf   = (short*)(ws + 6291456);                       // 6.29 MB
  unsigned short* bgate = (unsigned short*)(ws + 12582912);
  unsigned short* qkbf  = (unsigned short*)(ws + 25165824);
  short* xnbf  = (short*)(ws + 37748736);                      // 3.15 MB
  short* w12bf = (short*)(ws + 40894464);                      // 295 KB
  short* wobf  = (short*)(ws + 41189376);                      // 147 KB
  short* o1bf  = (short*)(ws + 41943040);
  short* qbf   = (short*)(ws + 50331648);
  short* kbf   = (short*)(ws + 56623104);
  short* vtbf  = (short*)(ws + 62914560);
  float* itv   = (float*)(ws + 69648384);
  float* ftv   = (float*)(ws + 69779456);
  float* Ev    = (float*)(ws + 69910528);
  float* Rpv   = (float*)(ws + 70041600);
  float* dsv   = (float*)(ws + 70172672);

  k1a_ln<<<728, 256, 0, stream>>>(x, ln_g, ln_b, w1, w2, wo, xnbf, w12bf, wobf);
  k1b_gemm<<<512, 256, 0, stream>>>(xnbf, w12bf, b1, b2, abf, bgate);
  k2bv<<<512, 256, 0, stream>>>(abf, cw, cb, qw, qb, kw, kb, vw, vb, qkbf, qbf, kbf, vbf, vtbf);
  k2c_gates<<<128, 256, 0, stream>>>(qbf, kbf, vbf, wi, bi, wf, bff, itv, ftv);
  k3_scan<<<32, 256, 0, stream>>>(itv, ftv, Ev, Rpv, dsv);
  k4_attn<<<512, 256, 0, stream>>>(qbf, kbf, vtbf, Ev, Rpv, dsv, gn_g, gn_b,
                                   qkbf, bgate, skip, o1bf);
  k5_gemm<<<256, 256, 0, stream>>>(o1bf, wobf, bo, x, out);
}

// Round 18
// 75.330 us; speedup vs baseline: 1.0638x; 1.0462x over previous
//
#include <hip/hip_runtime.h>
#include <cstdint>

#define TAU_ 9.797958971132712f

typedef __attribute__((ext_vector_type(4))) float f32x4;
typedef __attribute__((ext_vector_type(8))) short short8;

#define DEV static __device__ __forceinline__

DEV unsigned short f2bf(float f){
  union { float f; unsigned u; } v; v.f = f;
  unsigned r = v.u + 0x7FFFu + ((v.u >> 16) & 1u);
  return (unsigned short)(r >> 16);
}
DEV float bf2f(unsigned short u){
  union { unsigned u; float f; } v; v.u = ((unsigned)u) << 16; return v.f;
}
DEV unsigned pack2bf(float a, float b){
  unsigned r;
  asm("v_cvt_pk_bf16_f32 %0, %1, %2" : "=v"(r) : "v"(a), "v"(b));
  return r;
}
DEV f32x4 ld_bf4(const unsigned short* p){
  uint2 r = *(const uint2*)p;
  f32x4 o;
  o[0] = bf2f((unsigned short)(r.x & 0xffff));
  o[1] = bf2f((unsigned short)(r.x >> 16));
  o[2] = bf2f((unsigned short)(r.y & 0xffff));
  o[3] = bf2f((unsigned short)(r.y >> 16));
  return o;
}
DEV float siluf_(float x){ return x / (1.f + __expf(-x)); }
DEV float logsigf_(float x){ return fminf(x, 0.f) - log1pf(__expf(-fabsf(x))); }

// ---------------- K1a: LayerNorm (blocks 0-511) + weight f32->bf16 convert (tail) ----------------
__global__ __launch_bounds__(256) void k1a_ln(
    const float* __restrict__ x, const float* __restrict__ ln_g, const float* __restrict__ ln_b,
    const float* __restrict__ w1, const float* __restrict__ w2, const float* __restrict__ wo,
    short* __restrict__ xnbf, short* __restrict__ w12bf, short* __restrict__ wobf)
{
  const int tid = threadIdx.x;
  if(blockIdx.x >= 512){
    const int idx4 = (blockIdx.x - 512) * 256 + tid;   // 216*256 = 55296 f32x4 units
    const float* src; short* dst; int off;
    if(idx4 < 18432)      { src = w1; dst = w12bf;         off = idx4; }
    else if(idx4 < 36864) { src = w2; dst = w12bf + 73728; off = idx4 - 18432; }
    else                  { src = wo; dst = wobf;          off = idx4 - 36864; }
    f32x4 v = *(const f32x4*)(src + off * 4);
    uint2 pk; pk.x = pack2bf(v[0], v[1]); pk.y = pack2bf(v[2], v[3]);
    *(uint2*)(dst + off * 4) = pk;
    return;
  }
  const int t = blockIdx.x * 16 + (tid >> 4);
  const int g = tid & 15;
  const float* xr = x + (long)t * 192 + g * 12;
  f32x4 v0 = *(const f32x4*)(xr);
  f32x4 v1 = *(const f32x4*)(xr + 4);
  f32x4 v2 = *(const f32x4*)(xr + 8);
  float s  = v0[0]+v0[1]+v0[2]+v0[3] + v1[0]+v1[1]+v1[2]+v1[3] + v2[0]+v2[1]+v2[2]+v2[3];
  float sq = v0[0]*v0[0]+v0[1]*v0[1]+v0[2]*v0[2]+v0[3]*v0[3]
           + v1[0]*v1[0]+v1[1]*v1[1]+v1[2]*v1[2]+v1[3]*v1[3]
           + v2[0]*v2[0]+v2[1]*v2[1]+v2[2]*v2[2]+v2[3]*v2[3];
  s  += __shfl_xor(s, 1);  s  += __shfl_xor(s, 2);  s  += __shfl_xor(s, 4);  s  += __shfl_xor(s, 8);
  sq += __shfl_xor(sq, 1); sq += __shfl_xor(sq, 2); sq += __shfl_xor(sq, 4); sq += __shfl_xor(sq, 8);
  const float mean = s * (1.f/192.f);
  const float rstd = rsqrtf(sq * (1.f/192.f) - mean * mean + 1e-5f);
  const int c0 = g * 12;
  f32x4 g0 = *(const f32x4*)(ln_g + c0),     b0 = *(const f32x4*)(ln_b + c0);
  f32x4 g1 = *(const f32x4*)(ln_g + c0 + 4), b1 = *(const f32x4*)(ln_b + c0 + 4);
  f32x4 g2 = *(const f32x4*)(ln_g + c0 + 8), b2 = *(const f32x4*)(ln_b + c0 + 8);
  unsigned pk[6];
  pk[0] = pack2bf((v0[0]-mean)*rstd*g0[0]+b0[0], (v0[1]-mean)*rstd*g0[1]+b0[1]);
  pk[1] = pack2bf((v0[2]-mean)*rstd*g0[2]+b0[2], (v0[3]-mean)*rstd*g0[3]+b0[3]);
  pk[2] = pack2bf((v1[0]-mean)*rstd*g1[0]+b1[0], (v1[1]-mean)*rstd*g1[1]+b1[1]);
  pk[3] = pack2bf((v1[2]-mean)*rstd*g1[2]+b1[2], (v1[3]-mean)*rstd*g1[3]+b1[3]);
  pk[4] = pack2bf((v2[0]-mean)*rstd*g2[0]+b2[0], (v2[1]-mean)*rstd*g2[1]+b2[1]);
  pk[5] = pack2bf((v2[2]-mean)*rstd*g2[2]+b2[2], (v2[3]-mean)*rstd*g2[3]+b2[3]);
  uint2* xo = (uint2*)(xnbf + (long)t * 192 + g * 12);
  xo[0] = make_uint2(pk[0], pk[1]);
  xo[1] = make_uint2(pk[2], pk[3]);
  xo[2] = make_uint2(pk[4], pk[5]);
}

// ---------------- K1b: dual GEMM, M-tile 128, bf16 weights ----------------
__global__ __launch_bounds__(256) void k1b_gemm(
    const short* __restrict__ xnbf, const short* __restrict__ w12bf,
    const float* __restrict__ b1, const float* __restrict__ b2,
    unsigned short* __restrict__ abf, unsigned short* __restrict__ bgate)
{
  __shared__ short wt[18432];                          // 96*192 bf16 = 36.9 KB
  const int tid = threadIdx.x;
  const int ntg = blockIdx.x & 7;
  const int t0 = (blockIdx.x >> 3) * 128;
  {
    const short* src = w12bf + (long)ntg * 96 * 192;
    #pragma unroll
    for(int i = 0; i < 9; i++){
      const int u = i * 256 + tid;                     // 16B unit, 0..2303
      const int row = u / 24;
      const int dst = (u * 16) ^ ((row & 7) << 4);
      *(short8*)((char*)wt + dst) = *(const short8*)(src + u * 8);
    }
  }
  __syncthreads();
  const int widx = tid >> 6, lane = tid & 63, qg = lane >> 4, l16 = lane & 15;
  const int m0 = t0 + widx * 32;
  f32x4 acc[2][6];
  #pragma unroll
  for(int mt = 0; mt < 2; mt++)
    #pragma unroll
    for(int nt = 0; nt < 6; nt++) acc[mt][nt] = (f32x4){0.f,0.f,0.f,0.f};
  const short* xrow0 = xnbf + (long)(m0 + l16) * 192;
  const short* xrow1 = xnbf + (long)(m0 + 16 + l16) * 192;
  #pragma unroll
  for(int kc = 0; kc < 6; kc++){
    short8 af0 = *(const short8*)(xrow0 + kc * 32 + 8 * qg);
    short8 af1 = *(const short8*)(xrow1 + kc * 32 + 8 * qg);
    #pragma unroll
    for(int nt = 0; nt < 6; nt++){
      const int row = nt * 16 + l16;
      int byte = row * 384 + (kc * 32 + 8 * qg) * 2;
      byte ^= (row & 7) << 4;
      short8 bfr = *(const short8*)((const char*)wt + byte);
      acc[0][nt] = __builtin_amdgcn_mfma_f32_16x16x32_bf16(af0, bfr, acc[0][nt], 0, 0, 0);
      acc[1][nt] = __builtin_amdgcn_mfma_f32_16x16x32_bf16(af1, bfr, acc[1][nt], 0, 0, 0);
    }
  }
  const int half = ntg >> 2;
  const float* bias = half ? b2 : b1;
  const int ncol = (ntg & 3) * 96;
  #pragma unroll
  for(int mt = 0; mt < 2; mt++){
    #pragma unroll
    for(int nt = 0; nt < 6; nt++){
      const int n = ncol + nt * 16 + l16;
      const float bs = bias[n];
      #pragma unroll
      for(int r = 0; r < 4; r++){
        const int trow = m0 + mt * 16 + 4 * qg + r;
        float v = acc[mt][nt][r] + bs;
        if(half) bgate[(long)trow * 384 + n] = f2bf(siluf_(v));
        else     abf[(long)trow * 384 + n] = f2bf(v);
      }
    }
  }
}

// ---------------- K2bv: dwconv+silu -> qkbuf bf16, q/k proj -> bf16, v -> vbf + vtbf^T ----
__global__ __launch_bounds__(256) void k2bv(
    const unsigned short* __restrict__ abf,
    const float* __restrict__ cw, const float* __restrict__ cb,
    const float* __restrict__ qw, const float* __restrict__ qb,
    const float* __restrict__ kw, const float* __restrict__ kb,
    const float* __restrict__ vw, const float* __restrict__ vb,
    unsigned short* __restrict__ qkbf, short* __restrict__ qbf, short* __restrict__ kbf,
    short* __restrict__ vbf, short* __restrict__ vtbf)
{
  __shared__ float vt[64][97];
  const int tid = threadIdx.x;
  const int bh = blockIdx.x >> 4;
  const int b = bh >> 2, h = bh & 3;
  const int s0 = (blockIdx.x & 15) << 6;
  #pragma unroll
  for(int it = 0; it < 6; it++){
    const int f = it * 256 + tid;                     // 64 sl * 24 c4l
    const int sl = f / 24, c4l = f % 24;
    const int c4 = h * 24 + c4l;
    const int s = s0 + sl;
    const long t = (long)b * 1024 + s;
    const long abase = t * 384 + c4 * 4;
    f32x4 am = ld_bf4(abf + abase);
    f32x4 al = (s > 0)    ? ld_bf4(abf + abase - 384) : (f32x4){0.f,0.f,0.f,0.f};
    f32x4 ar = (s < 1023) ? ld_bf4(abf + abase + 384) : (f32x4){0.f,0.f,0.f,0.f};
    f32x4 cw0 = *(const f32x4*)(cw + c4 * 12);
    f32x4 cw1 = *(const f32x4*)(cw + c4 * 12 + 4);
    f32x4 cw2 = *(const f32x4*)(cw + c4 * 12 + 8);
    f32x4 cb4 = *(const f32x4*)(cb + c4 * 4);
    f32x4 in;
    in[0] = siluf_(cb4[0] + al[0]*cw0[0] + am[0]*cw0[1] + ar[0]*cw0[2]);
    in[1] = siluf_(cb4[1] + al[1]*cw0[3] + am[1]*cw1[0] + ar[1]*cw1[1]);
    in[2] = siluf_(cb4[2] + al[2]*cw1[2] + am[2]*cw1[3] + ar[2]*cw2[0]);
    in[3] = siluf_(cb4[3] + al[3]*cw2[1] + am[3]*cw2[2] + ar[3]*cw2[3]);
    {
      uint2 pk; pk.x = pack2bf(in[0], in[1]); pk.y = pack2bf(in[2], in[3]);
      *(uint2*)(qkbf + abase) = pk;
    }
    const long base = ((long)(b * 4 + h) * 1024 + s) * 96 + c4l * 4;
    {
      const float* w = qw + c4 * 16;
      float v0 = qb[c4*4+0] + w[0]*in[0]  + w[1]*in[1]  + w[2]*in[2]  + w[3]*in[3];
      float v1 = qb[c4*4+1] + w[4]*in[0]  + w[5]*in[1]  + w[6]*in[2]  + w[7]*in[3];
      float v2 = qb[c4*4+2] + w[8]*in[0]  + w[9]*in[1]  + w[10]*in[2] + w[11]*in[3];
      float v3 = qb[c4*4+3] + w[12]*in[0] + w[13]*in[1] + w[14]*in[2] + w[15]*in[3];
      uint2 pk; pk.x = pack2bf(v0, v1); pk.y = pack2bf(v2, v3);
      *(uint2*)(qbf + base) = pk;
    }
    {
      const float* w = kw + c4 * 16;
      float v0 = kb[c4*4+0] + w[0]*in[0]  + w[1]*in[1]  + w[2]*in[2]  + w[3]*in[3];
      float v1 = kb[c4*4+1] + w[4]*in[0]  + w[5]*in[1]  + w[6]*in[2]  + w[7]*in[3];
      float v2 = kb[c4*4+2] + w[8]*in[0]  + w[9]*in[1]  + w[10]*in[2] + w[11]*in[3];
      float v3 = kb[c4*4+3] + w[12]*in[0] + w[13]*in[1] + w[14]*in[2] + w[15]*in[3];
      uint2 pk; pk.x = pack2bf(v0, v1); pk.y = pack2bf(v2, v3);
      *(uint2*)(kbf + base) = pk;
    }
    {
      const float* w = vw + c4 * 16;
      float vv[4];
      #pragma unroll
      for(int o = 0; o < 4; o++){
        float v = vb[c4*4+o] + w[o*4]*am[0] + w[o*4+1]*am[1] + w[o*4+2]*am[2] + w[o*4+3]*am[3];
        vv[o] = v;
        vt[sl][c4l * 4 + o] = v;
      }
      uint2 pk; pk.x = pack2bf(vv[0], vv[1]); pk.y = pack2bf(vv[2], vv[3]);
      *(uint2*)(vbf + abase) = pk;            // flat [t][384] for gate GEMM
    }
  }
  __syncthreads();
  #pragma unroll
  for(int it = 0; it < 24; it++){
    const int f = it * 256 + tid;                    // 96 d * 64 sl
    const int d = f >> 6, sl = f & 63;
    vtbf[((long)bh * 96 + d) * 1024 + s0 + sl] = (short)f2bf(vt[sl][d]);
  }
}

// ---------------- K2c: gate GEMM  C[8192x8] = gi @ [wi;wf]^T  (MFMA 16x16x32) ----------------
__global__ __launch_bounds__(256) void k2c_gates(
    const short* __restrict__ qbf, const short* __restrict__ kbf, const short* __restrict__ vbf,
    const float* __restrict__ wi, const float* __restrict__ bi,
    const float* __restrict__ wf, const float* __restrict__ bff,
    float* __restrict__ itv, float* __restrict__ ftv)
{
  __shared__ short wg[8 * 1160];                      // 8 gate rows, padded stride (18.6 KB)
  const int tid = threadIdx.x;
  const int t0 = blockIdx.x * 64;
  #pragma unroll
  for(int i = 0; i < 9; i++){
    const int u = i * 256 + tid;                      // f32x4 units, 2304 = 8 rows * 288
    const int row = u / 288, col4 = u % 288;
    const float* src = ((row < 4) ? wi + row * 1152 : wf + (row - 4) * 1152) + col4 * 4;
    f32x4 v = *(const f32x4*)src;
    uint2 pk; pk.x = pack2bf(v[0], v[1]); pk.y = pack2bf(v[2], v[3]);
    *(uint2*)(&wg[row * 1160 + col4 * 4]) = pk;
  }
  __syncthreads();
  const int w = tid >> 6, lane = tid & 63, qg = lane >> 4, l16 = lane & 15;
  const int tw = t0 + w * 16;
  const int tA = tw + l16;
  const int b = tA >> 10, s = tA & 1023;
  f32x4 acc = (f32x4){0.f,0.f,0.f,0.f};
  #pragma unroll
  for(int kc = 0; kc < 36; kc++){
    const int blk = kc / 3;                           // 96-block 0..11 (compile-time)
    const int off = (kc % 3) * 32 + qg * 8;
    short8 af;
    if(blk < 4)      af = *(const short8*)(qbf + ((long)(b*4+blk)*1024 + s)*96 + off);
    else if(blk < 8) af = *(const short8*)(kbf + ((long)(b*4+blk-4)*1024 + s)*96 + off);
    else             af = *(const short8*)(vbf + (long)tA*384 + (blk-8)*96 + off);
    short8 bf8 = *(const short8*)(&wg[(l16 & 7) * 1160 + kc * 32 + qg * 8]);
    acc = __builtin_amdgcn_mfma_f32_16x16x32_bf16(af, bf8, acc, 0, 0, 0);
  }
  if(l16 < 8){
    const int gh = l16 & 3;
    const float bias = (l16 < 4) ? bi[gh] : bff[gh];
    float* dst = (l16 < 4) ? itv : ftv;
    #pragma unroll
    for(int r = 0; r < 4; r++){
      const int t = tw + 4 * qg + r;
      dst[((long)((t >> 10) * 4 + gh)) * 1024 + (t & 1023)] = acc[r] + bias;
    }
  }
}

// ---------------- K4: flash mLSTM attention + fused per-bh scan (was k3) ----------------
__global__ __launch_bounds__(256, 2) void k4_attn(
    const short* __restrict__ qbf, const short* __restrict__ kbf, const short* __restrict__ vtbf,
    const float* __restrict__ itv, const float* __restrict__ ftv,
    const float* __restrict__ gn_g, const float* __restrict__ gn_b,
    const unsigned short* __restrict__ qkbf, const unsigned short* __restrict__ bgate,
    const float* __restrict__ skip, short* __restrict__ o1bf)
{
  __shared__ short kbuf[2][64 * 104];
  __shared__ short vbuf[2][96 * 72];
  __shared__ short P[4][16][72];
  __shared__ float eall[1024];
  __shared__ float rpL[64], dsL[64];
  __shared__ float sb[256];
  const int tid = threadIdx.x;
  const int w = tid >> 6, lane = tid & 63, qg = lane >> 4, l16 = lane & 15;
  const int xcd = blockIdx.x & 7, q = blockIdx.x >> 3;
  const int bh = ((q & 3) << 3) | xcd;
  const int qh = q >> 2;
  const int ib = (q < 32) ? (15 - qh) : (qh - 8);
  const int i0w = ib * 64 + w * 16;
  const long qkbase = (long)bh * 1024;
  const int nj = ib + 1;

  const int rK0 = tid / 12,        cK0 = tid % 12;
  const int rK1 = (tid+256) / 12,  cK1 = (tid+256) % 12;
  const int rK2 = (tid+512) / 12,  cK2 = (tid+512) % 12;
  const int dV0 = tid >> 3,        cV0 = tid & 7;
  const int dV1 = (tid+256) >> 3,  cV1 = (tid+256) & 7;
  const int dV2 = (tid+512) >> 3,  cV2 = (tid+512) & 7;
  short8 sk0, sk1, sk2, sv0, sv1, sv2;
  const short* kgb = kbf + qkbase * 96;
  const short* vgb = vtbf + (long)bh * 96 * 1024;

#define STAGE_LOAD(J0)                                              \
  {                                                                 \
    const int j0_ = (J0);                                           \
    sk0 = *(const short8*)(kgb + (j0_ + rK0) * 96 + cK0 * 8);       \
    sk1 = *(const short8*)(kgb + (j0_ + rK1) * 96 + cK1 * 8);       \
    sk2 = *(const short8*)(kgb + (j0_ + rK2) * 96 + cK2 * 8);       \
    sv0 = *(const short8*)(vgb + (long)dV0 * 1024 + j0_ + cV0 * 8); \
    sv1 = *(const short8*)(vgb + (long)dV1 * 1024 + j0_ + cV1 * 8); \
    sv2 = *(const short8*)(vgb + (long)dV2 * 1024 + j0_ + cV2 * 8); \
  }

#define STAGE_WRITE(B)                                   \
  {                                                      \
    *(short8*)(&kbuf[B][rK0 * 104 + cK0 * 8]) = sk0;     \
    *(short8*)(&kbuf[B][rK1 * 104 + cK1 * 8]) = sk1;     \
    *(short8*)(&kbuf[B][rK2 * 104 + cK2 * 8]) = sk2;     \
    *(short8*)(&vbuf[B][dV0 * 72 + cV0 * 8]) = sv0;      \
    *(short8*)(&vbuf[B][dV1 * 72 + cV1 * 8]) = sv1;      \
    *(short8*)(&vbuf[B][dV2 * 72 + cV2 * 8]) = sv2;      \
  }

  // issue first K/V tile loads + Q loads early: latency hides under the scan below
  STAGE_LOAD(0);
  short8 qf[3];
  #pragma unroll
  for(int kc = 0; kc < 3; kc++)
    qf[kc] = *(const short8*)(qbf + (qkbase + i0w + l16) * 96 + kc * 32 + 8 * qg);

  // ---- fused per-bh scan (identical math to old k3_scan) ----
  {
    const long sbase = qkbase + tid * 4;
    f32x4 f4 = *(const f32x4*)(ftv + sbase);
    const float l0 = logsigf_(f4[0]);
    const float l1 = logsigf_(f4[1]);
    const float l2 = logsigf_(f4[2]);
    const float l3 = logsigf_(f4[3]);
    float c0 = l0, c1 = l0 + l1, c2 = c1 + l2, c3 = c2 + l3;
    sb[tid] = c3;
    __syncthreads();
    for(int off = 1; off < 256; off <<= 1){
      float mine = sb[tid];
      float oth = (tid >= off) ? sb[tid - off] : 0.f;
      __syncthreads();
      sb[tid] = mine + oth;
      __syncthreads();
    }
    const float excl = (tid > 0) ? sb[tid - 1] : 0.f;
    c0 += excl; c1 += excl; c2 += excl; c3 += excl;
    f32x4 i4 = *(const f32x4*)(itv + sbase);
    const float m0 = i4[0] - c0, m1 = i4[1] - c1, m2 = i4[2] - c2, m3 = i4[3] - c3;
    const float x1 = fmaxf(m0, m1), x2 = fmaxf(x1, m2), x3 = fmaxf(x2, m3);
    __syncthreads();
    sb[tid] = x3;
    __syncthreads();
    for(int off = 1; off < 256; off <<= 1){
      float mine = sb[tid];
      float oth = (tid >= off) ? sb[tid - off] : -3.4e38f;
      __syncthreads();
      sb[tid] = fmaxf(mine, oth);
      __syncthreads();
    }
    const float exm = (tid > 0) ? sb[tid - 1] : -3.4e38f;
    const float M0 = fmaxf(m0, exm);
    const float M1 = fmaxf(x1, exm);
    const float M2 = fmaxf(x2, exm);
    const float M3 = fmaxf(x3, exm);
    f32x4 ev;
    ev[0] = __expf(m0); ev[1] = __expf(m1); ev[2] = __expf(m2); ev[3] = __expf(m3);
    *(f32x4*)(&eall[tid * 4]) = ev;
    float rpv4[4], dsv4[4];
    rpv4[0] = __expf(-M0) * (1.f/TAU_); rpv4[1] = __expf(-M1) * (1.f/TAU_);
    rpv4[2] = __expf(-M2) * (1.f/TAU_); rpv4[3] = __expf(-M3) * (1.f/TAU_);
    dsv4[0] = __expf(-(c0 + M0)); dsv4[1] = __expf(-(c1 + M1));
    dsv4[2] = __expf(-(c2 + M2)); dsv4[3] = __expf(-(c3 + M3));
    const int p0 = tid * 4;
    #pragma unroll
    for(int e = 0; e < 4; e++){
      const int rel = p0 + e - ib * 64;
      if(rel >= 0 && rel < 64){ rpL[rel] = rpv4[e]; dsL[rel] = dsv4[e]; }
    }
    __syncthreads();
  }
  const float rp = rpL[w * 16 + l16];
  const float ds = dsL[w * 16 + l16];

  f32x4 acc[6];
  #pragma unroll
  for(int dt = 0; dt < 6; dt++) acc[dt] = (f32x4){0.f,0.f,0.f,0.f};
  float bp = 0.f;

  int cur = 0;
  for(int jt = 0; jt < nj; jt++){
    STAGE_WRITE(cur);
    __syncthreads();
    if(jt + 1 < nj) STAGE_LOAD((jt + 1) * 64);

    const int j0 = jt * 64;
    const bool diag = (jt == nj - 1);
    const int i = i0w + l16;
    __builtin_amdgcn_s_setprio(1);
    #pragma unroll
    for(int jsub = 0; jsub < 4; jsub++){
      f32x4 C = (f32x4){0.f,0.f,0.f,0.f};
      #pragma unroll
      for(int kc = 0; kc < 3; kc++){
        short8 kf = *(const short8*)(&kbuf[cur][(jsub*16 + l16) * 104 + kc * 32 + 8 * qg]);
        C = __builtin_amdgcn_mfma_f32_16x16x32_bf16(kf, qf[kc], C, 0, 0, 0);
      }
      f32x4 e4 = *(const f32x4*)(&eall[j0 + jsub * 16 + 4 * qg]);
      float v0 = C[0] * e4[0];
      float v1 = C[1] * e4[1];
      float v2 = C[2] * e4[2];
      float v3 = C[3] * e4[3];
      if(diag){
        const int jb = j0 + jsub * 16 + 4 * qg;
        if(jb + 0 > i) v0 = 0.f;
        if(jb + 1 > i) v1 = 0.f;
        if(jb + 2 > i) v2 = 0.f;
        if(jb + 3 > i) v3 = 0.f;
      }
      bp += v0 + v1 + v2 + v3;
      uint2 pw; pw.x = pack2bf(v0, v1); pw.y = pack2bf(v2, v3);
      *(uint2*)(&P[w][l16][jsub * 16 + 4 * qg]) = pw;
    }
    asm volatile("s_waitcnt lgkmcnt(0)" ::: "memory");
    #pragma unroll
    for(int ksub = 0; ksub < 2; ksub++){
      short8 pa = *(const short8*)(&P[w][l16][ksub * 32 + 8 * qg]);
      #pragma unroll
      for(int dt = 0; dt < 6; dt++){
        short8 vf = *(const short8*)(&vbuf[cur][(dt * 16 + l16) * 72 + ksub * 32 + 8 * qg]);
        acc[dt] = __builtin_amdgcn_mfma_f32_16x16x32_bf16(pa, vf, acc[dt], 0, 0, 0);
      }
    }
    __builtin_amdgcn_s_setprio(0);
    cur ^= 1;
  }
#undef STAGE_LOAD
#undef STAGE_WRITE

  // ---- T14: issue epilogue global loads NOW; consume after GN math ----
  const int head = bh & 3, bb = bh >> 2;
  short8 q8v[3], g8v[3];
  f32x4 s0v[3], s1v[3];
  long offv[3];
  #pragma unroll
  for(int u2 = 0; u2 < 3; u2++){
    const int f = u2 * 256 + tid;
    const int row = f / 12, c8 = f % 12;
    const long off = ((long)(bb * 1024 + ib * 64 + row)) * 384 + head * 96 + c8 * 8;
    offv[u2] = off;
    q8v[u2] = *(const short8*)((const short*)qkbf + off);
    g8v[u2] = *(const short8*)((const short*)bgate + off);
    s0v[u2] = *(const f32x4*)(skip + head * 96 + c8 * 8);
    s1v[u2] = *(const f32x4*)(skip + head * 96 + c8 * 8 + 4);
  }

  float bsum = bp;
  bsum += __shfl_xor(bsum, 16);
  bsum += __shfl_xor(bsum, 32);
  const float bfull = bsum * rp;
  const float den = fmaxf(fabsf(bfull), ds) + 1e-6f;
  const float sc = rp / den;
  float srow[4];
  #pragma unroll
  for(int r = 0; r < 4; r++) srow[r] = __shfl(sc, 4 * qg + r);
  float hv[6][4], mu[4], rs[4];
  #pragma unroll
  for(int r = 0; r < 4; r++){
    float sm = 0.f, sq = 0.f;
    #pragma unroll
    for(int dt = 0; dt < 6; dt++){
      const float h = acc[dt][r] * srow[r];
      hv[dt][r] = h; sm += h; sq += h * h;
    }
    sm += __shfl_xor(sm, 1); sm += __shfl_xor(sm, 2); sm += __shfl_xor(sm, 4); sm += __shfl_xor(sm, 8);
    sq += __shfl_xor(sq, 1); sq += __shfl_xor(sq, 2); sq += __shfl_xor(sq, 4); sq += __shfl_xor(sq, 8);
    const float m_ = sm * (1.f/96.f);
    mu[r] = m_;
    rs[r] = rsqrtf(sq * (1.f/96.f) - m_ * m_ + 1e-5f);
  }
  __syncthreads();
  short* hstage = &kbuf[0][0];
  #pragma unroll
  for(int dt = 0; dt < 6; dt++){
    const int col = head * 96 + dt * 16 + l16;
    const float g  = gn_g[col];
    const float be = gn_b[col];
    #pragma unroll
    for(int r = 0; r < 4; r++){
      const float hn = (hv[dt][r] - mu[r]) * rs[r] * g + be;
      hstage[(w * 16 + 4 * qg + r) * 104 + dt * 16 + l16] = (short)f2bf(hn);
    }
  }
  __syncthreads();
  #pragma unroll
  for(int u2 = 0; u2 < 3; u2++){
    const int f = u2 * 256 + tid;
    const int row = f / 12, c8 = f % 12;
    short8 h8 = *(const short8*)(hstage + row * 104 + c8 * 8);
    short8 q8 = q8v[u2];
    short8 g8 = g8v[u2];
    float o[8];
    #pragma unroll
    for(int i = 0; i < 8; i++){
      const float sk = (i < 4) ? s0v[u2][i] : s1v[u2][i - 4];
      o[i] = (bf2f((unsigned short)h8[i]) + sk * bf2f((unsigned short)q8[i]))
             * bf2f((unsigned short)g8[i]);
    }
    union { short8 s; unsigned u4[4]; } ov;
    ov.u4[0] = pack2bf(o[0], o[1]); ov.u4[1] = pack2bf(o[2], o[3]);
    ov.u4[2] = pack2bf(o[4], o[5]); ov.u4[3] = pack2bf(o[6], o[7]);
    *(short8*)(o1bf + offv[u2]) = ov.s;
  }
}

// ---------------- K5: out = o1 @ wo^T + bo + x, M-tile 128, bf16 weights ----------------
__global__ __launch_bounds__(256) void k5_gemm(
    const short* __restrict__ o1bf, const short* __restrict__ wobf,
    const float* __restrict__ bo, const float* __restrict__ x, float* __restrict__ out)
{
  __shared__ short wt[18432];                          // 48*384 bf16 = 36864 B
  const int tid = threadIdx.x;
  const int ng = blockIdx.x & 3;
  const int t0 = (blockIdx.x >> 2) * 128;
  {
    const short* src = wobf + (long)ng * 48 * 384;
    #pragma unroll
    for(int i = 0; i < 9; i++){
      const int u = i * 256 + tid;                     // 16B units, 0..2303
      const int row = u / 48;
      const int dst = (u * 16) ^ ((row & 7) << 4);
      *(short8*)((char*)wt + dst) = *(const short8*)(src + u * 8);
    }
  }
  __syncthreads();
  const int widx = tid >> 6, lane = tid & 63, qg = lane >> 4, l16 = lane & 15;
  const int m0 = t0 + widx * 32;
  f32x4 acc[2][3];
  #pragma unroll
  for(int mt = 0; mt < 2; mt++)
    #pragma unroll
    for(int nt = 0; nt < 3; nt++) acc[mt][nt] = (f32x4){0.f,0.f,0.f,0.f};
  const short* arow0 = o1bf + (long)(m0 + l16) * 384;
  const short* arow1 = o1bf + (long)(m0 + 16 + l16) * 384;
  #pragma unroll
  for(int kc = 0; kc < 12; kc++){
    short8 af0 = *(const short8*)(arow0 + kc * 32 + 8 * qg);
    short8 af1 = *(const short8*)(arow1 + kc * 32 + 8 * qg);
    #pragma unroll
    for(int nt = 0; nt < 3; nt++){
      const int row = nt * 16 + l16;
      int byte = row * 768 + kc * 64 + qg * 16;
      byte ^= (row & 7) << 4;
      short8 bfr = *(const short8*)((const char*)wt + byte);
      acc[0][nt] = __builtin_amdgcn_mfma_f32_16x16x32_bf16(af0, bfr, acc[0][nt], 0, 0, 0);
      acc[1][nt] = __builtin_amdgcn_mfma_f32_16x16x32_bf16(af1, bfr, acc[1][nt], 0, 0, 0);
    }
  }
  #pragma unroll
  for(int mt = 0; mt < 2; mt++){
    #pragma unroll
    for(int nt = 0; nt < 3; nt++){
      const int n = ng * 48 + nt * 16 + l16;
      const float b_ = bo[n];
      #pragma unroll
      for(int r = 0; r < 4; r++){
        const int trow = m0 + mt * 16 + 4 * qg + r;
        out[(long)trow * 192 + n] = acc[mt][nt][r] + b_ + x[(long)trow * 192 + n];
      }
    }
  }
}

// ---------------- launch ----------------
extern "C" void kernel_launch(void* const* d_in, const int* in_sizes, int n_in,
                              void* d_out, int out_size, void* d_ws, size_t ws_size,
                              hipStream_t stream)
{
  (void)in_sizes; (void)n_in; (void)out_size; (void)ws_size;
  const float* x    = (const float*)d_in[0];
  const float* ln_g = (const float*)d_in[1];
  const float* ln_b = (const float*)d_in[2];
  const float* w1   = (const float*)d_in[3];
  const float* b1   = (const float*)d_in[4];
  const float* w2   = (const float*)d_in[5];
  const float* b2   = (const float*)d_in[6];
  const float* cw   = (const float*)d_in[7];
  const float* cb   = (const float*)d_in[8];
  const float* qw   = (const float*)d_in[9];
  const float* qb   = (const float*)d_in[10];
  const float* kw   = (const float*)d_in[11];
  const float* kb   = (const float*)d_in[12];
  const float* vw   = (const float*)d_in[13];
  const float* vb   = (const float*)d_in[14];
  const float* wi   = (const float*)d_in[15];
  const float* bi   = (const float*)d_in[16];
  const float* wf   = (const float*)d_in[17];
  const float* bff  = (const float*)d_in[18];
  const float* gn_g = (const float*)d_in[19];
  const float* gn_b = (const float*)d_in[20];
  const float* wo   = (const float*)d_in[21];
  const float* bo   = (const float*)d_in[22];
  const float* skip = (const float*)d_in[23];
  float* out = (float*)d_out;

  char* ws = (char*)d_ws;
  unsigned short* abf   = (unsigned short*)(ws + 0);           // 6.29 MB
  short* vbf   = (short*)(ws + 6291456);                       // 6.29 MB
  unsigned short* bgate = (unsigned short*)(ws + 12582912);
  unsigned short* qkbf  = (unsigned short*)(ws + 25165824);
  short* xnbf  = (short*)(ws + 37748736);                      // 3.15 MB
  short* w12bf = (short*)(ws + 40894464);                      // 295 KB
  short* wobf  = (short*)(ws + 41189376);                      // 147 KB
  short* o1bf  = (short*)(ws + 41943040);
  short* qbf   = (short*)(ws + 50331648);
  short* kbf   = (short*)(ws + 56623104);
  short* vtbf  = (short*)(ws + 62914560);
  float* itv   = (float*)(ws + 69648384);
  float* ftv   = (float*)(ws + 69779456);

  k1a_ln<<<728, 256, 0, stream>>>(x, ln_g, ln_b, w1, w2, wo, xnbf, w12bf, wobf);
  k1b_gemm<<<512, 256, 0, stream>>>(xnbf, w12bf, b1, b2, abf, bgate);
  k2bv<<<512, 256, 0, stream>>>(abf, cw, cb, qw, qb, kw, kb, vw, vb, qkbf, qbf, kbf, vbf, vtbf);
  k2c_gates<<<128, 256, 0, stream>>>(qbf, kbf, vbf, wi, bi, wf, bff, itv, ftv);
  k4_attn<<<512, 256, 0, stream>>>(qbf, kbf, vtbf, itv, ftv, gn_g, gn_b,
                                   qkbf, bgate, skip, o1bf);
  k5_gemm<<<256, 256, 0, stream>>>(o1bf, wobf, bo, x, out);
}